// Round 4
// baseline (526.047 us; speedup 1.0000x reference)
//
#include <hip/hip_runtime.h>
#include <math.h>

#define N_NODES 50000
#define N_EDGES 800000
#define HDIM 128

// edge tile geometry: 96 edges/block -> 26880 B LDS -> 6 blocks/CU
#define EB 96
#define NWG_E 8334          // ceil(800000/96)
// zero region: agg (N+1 rows x 128 f32) + dxb (N+1 rows x 3 f32, padded to 16B)
#define ZERO_F4 1637533

typedef __attribute__((ext_vector_type(8))) short bf16x8;
typedef __attribute__((ext_vector_type(4))) float floatx4;

__device__ __forceinline__ unsigned f2bf_u(float f) {
    union { float f; unsigned u; } x; x.f = f;
    return (x.u + 0x7FFFu + ((x.u >> 16) & 1u)) >> 16;
}
__device__ __forceinline__ short f2bf(float f) { return (short)f2bf_u(f); }
__device__ __forceinline__ float bf2f(short s) {
    union { float f; unsigned u; } x; x.u = ((unsigned)(unsigned short)s) << 16;
    return x.f;
}
// packed bf16 pair: lo = bf16(a), hi = bf16(b)  (HW RNE, 1 instr)
__device__ __forceinline__ unsigned cvt_pk_bf16(float a, float b) {
    unsigned r;
    asm("v_cvt_pk_bf16_f32 %0, %1, %2" : "=v"(r) : "v"(a), "v"(b));
    return r;
}
__device__ __forceinline__ float bflo(unsigned u) {
    union { float f; unsigned u; } x; x.u = u << 16; return x.f;
}
__device__ __forceinline__ float bfhi(unsigned u) {
    union { float f; unsigned u; } x; x.u = u & 0xffff0000u; return x.f;
}
__device__ __forceinline__ float fast_rcp(float x) {
    float r; asm("v_rcp_f32 %0, %1" : "=v"(r) : "v"(x)); return r;
}
__device__ __forceinline__ float silu_f(float v) {
    return v * fast_rcp(1.0f + __expf(-v));
}

// async 16B/lane global->LDS DMA; lds base wave-uniform, HW adds lane*16.
__device__ __forceinline__ void gl_lds16(const void* g, void* l) {
    __builtin_amdgcn_global_load_lds(
        (const __attribute__((address_space(1))) unsigned int*)g,
        (__attribute__((address_space(3))) unsigned int*)l, 16, 0, 0);
}

// Storage-column permutation: storage j holds original activation column
// p(j) = (j&~31) + ((j&31)>>1) + (j&1)*16, so a lane's (c0, c0+16) acc pair
// lands in ADJACENT shorts -> one ds_write_b32 / ds_read_b32 per pair.
// Weights consuming these activations (We2, Wx1, Wh2) have K rows permuted
// by p() in the pack; MFMA contraction is K-order-invariant.
__device__ __forceinline__ int permk(int k) {
    return (k & ~31) + ((k & 31) >> 1) + (k & 1) * 16;
}

// ---- shared bodies ----
__device__ __forceinline__ void pack_w_body(int t, const float* We1, const float* We2,
                                            const float* Wx1, const float* Wh1,
                                            const float* Wh2, short* pw) {
    int u = t >> 9;
    const float* W; int K, base; bool pk;
    if (u < 9)       { W = We1; K = 273; base = 0;  pk = false; }
    else if (u < 13) { W = We2; K = 128; base = 9;  pk = true;  }
    else if (u < 17) { W = Wx1; K = 128; base = 13; pk = true;  }
    else if (u < 25) { W = Wh1; K = 256; base = 17; pk = false; }
    else             { W = Wh2; K = 128; base = 25; pk = true;  }
    int tl = t - base * 512;
    int lane = tl & 63;
    int ctk = tl >> 6;
    int ct = ctk & 7, kc = ctk >> 3;
    int c = ct * 16 + (lane & 15);
    int kb = kc * 32 + (lane >> 4) * 8;
    bf16x8 v;
#pragma unroll
    for (int j = 0; j < 8; ++j) {
        int k = kb + j;
        int ks = pk ? permk(k) : k;
        v[j] = (k < K) ? f2bf(W[(size_t)ks * HDIM + c]) : (short)0;
    }
    *(bf16x8*)&pw[(size_t)t * 8] = v;
}

__device__ __forceinline__ void pack_h_body(int t, const float* src, short* dst) {
    const float4* p = (const float4*)(src + (size_t)t * 8);
    float4 a = p[0], b = p[1];
    uint4 o;
    o.x = cvt_pk_bf16(a.x, a.y);
    o.y = cvt_pk_bf16(a.z, a.w);
    o.z = cvt_pk_bf16(b.x, b.y);
    o.w = cvt_pk_bf16(b.z, b.w);
    *(uint4*)(dst + (size_t)t * 8) = o;
}

// ---- fused prep 1: hist (4-shadow) | pack h | pack weights ----
__global__ __launch_bounds__(256)
void fused_prep1(const float* __restrict__ h, short* __restrict__ h_bf,
                 const float* __restrict__ We1, const float* __restrict__ We2,
                 const float* __restrict__ Wx1, const float* __restrict__ Wh1,
                 const float* __restrict__ Wh2, short* __restrict__ pw,
                 const int* __restrict__ ei, int* __restrict__ cnt4) {
    int bid = blockIdx.x, tid = threadIdx.x;
    if (bid < 3125) {                       // hist: 3125*256 == N_EDGES
        int e = bid * 256 + tid;
        atomicAdd(&cnt4[(tid & 3) * N_NODES + ei[N_EDGES + e]], 1);
    } else if (bid < 6250) {                // pack h: 3125*256 == N*H/8
        pack_h_body((bid - 3125) * 256 + tid, h, h_bf);
    } else {                                // pack weights
        int t = (bid - 6250) * 256 + tid;
        if (t < 29 * 512) pack_w_body(t, We1, We2, Wx1, Wh1, Wh2, pw);
    }
}

// ---- standalone versions (fallback path) ----
__global__ void pack_all_w(const float* __restrict__ We1, const float* __restrict__ We2,
                           const float* __restrict__ Wx1, const float* __restrict__ Wh1,
                           const float* __restrict__ Wh2, short* __restrict__ pw) {
    int t = blockIdx.x * 256 + threadIdx.x;
    if (t < 29 * 512) pack_w_body(t, We1, We2, Wx1, Wh1, Wh2, pw);
}

__global__ void pack_bf16_kernel(const float* __restrict__ src, short* __restrict__ dst,
                                 int n8) {
    int t = blockIdx.x * 256 + threadIdx.x;
    if (t < n8) pack_h_body(t, src, dst);
}

__global__ void hist_kernel(const int* __restrict__ ei, int* __restrict__ cnt) {
    int e = blockIdx.x * 256 + threadIdx.x;
    if (e < N_EDGES) atomicAdd(&cnt[ei[N_EDGES + e]], 1);
}

// int4-per-thread exclusive scan (fallback, n multiple of 4)
__global__ __launch_bounds__(1024)
void scan_kernel(const int* __restrict__ cnt, int* __restrict__ cursor, int n4) {
    __shared__ int wsum[16];
    __shared__ int s_carry;
    const int tid = threadIdx.x;
    const int lane = tid & 63, wid = tid >> 6;
    if (tid == 0) s_carry = 0;
    __syncthreads();
    for (int base = 0; base < n4; base += 1024) {
        int i = base + tid;
        int4 v = make_int4(0, 0, 0, 0);
        if (i < n4) v = ((const int4*)cnt)[i];
        int t0 = v.x, t1 = t0 + v.y, t2 = t1 + v.z, tot = t2 + v.w;
        int s = tot;
#pragma unroll
        for (int off = 1; off < 64; off <<= 1) {
            int sh = __shfl_up(s, off, 64);
            if (lane >= off) s += sh;
        }
        if (lane == 63) wsum[wid] = s;
        __syncthreads();
        if (tid < 16) {
            int t = wsum[tid];
            int sc = t;
#pragma unroll
            for (int off = 1; off < 16; off <<= 1) {
                int tt = __shfl_up(sc, off, 64);
                if (lane >= off) sc += tt;
            }
            wsum[tid] = sc - t;   // exclusive
        }
        __syncthreads();
        int excl = (s - tot) + wsum[wid] + s_carry;
        if (i < n4) {
            int4 o;
            o.x = excl; o.y = excl + t0; o.z = excl + t1; o.w = excl + t2;
            ((int4*)cursor)[i] = o;
        }
        __syncthreads();
        if (tid == 1023) s_carry = excl + tot;
        __syncthreads();
    }
}

// 4-shadow scan: degree(d) = sum_k cnt4[k][d]; cursor4[k][d] = csr_start(d)
// + sum_{j<k} cnt4[j][d]. Layout: shadow slices of 50000 ints (12500 int4).
__global__ __launch_bounds__(1024)
void scan4_kernel(const int* __restrict__ cnt4, int* __restrict__ cursor4, int n4) {
    __shared__ int wsum[16];
    __shared__ int s_carry;
    const int tid = threadIdx.x;
    const int lane = tid & 63, wid = tid >> 6;
    if (tid == 0) s_carry = 0;
    __syncthreads();
    for (int base = 0; base < n4; base += 1024) {
        int i = base + tid;
        int4 a0 = make_int4(0,0,0,0), a1 = a0, a2 = a0, a3 = a0;
        if (i < n4) {
            a0 = ((const int4*)cnt4)[i];
            a1 = ((const int4*)cnt4)[n4 + i];
            a2 = ((const int4*)cnt4)[2 * n4 + i];
            a3 = ((const int4*)cnt4)[3 * n4 + i];
        }
        int4 E;   // per-node total degree
        E.x = a0.x + a1.x + a2.x + a3.x;
        E.y = a0.y + a1.y + a2.y + a3.y;
        E.z = a0.z + a1.z + a2.z + a3.z;
        E.w = a0.w + a1.w + a2.w + a3.w;
        int t0 = E.x, t1 = t0 + E.y, t2 = t1 + E.z, tot = t2 + E.w;
        int s = tot;
#pragma unroll
        for (int off = 1; off < 64; off <<= 1) {
            int sh = __shfl_up(s, off, 64);
            if (lane >= off) s += sh;
        }
        if (lane == 63) wsum[wid] = s;
        __syncthreads();
        if (tid < 16) {
            int t = wsum[tid];
            int sc = t;
#pragma unroll
            for (int off = 1; off < 16; off <<= 1) {
                int tt = __shfl_up(sc, off, 64);
                if (lane >= off) sc += tt;
            }
            wsum[tid] = sc - t;   // exclusive
        }
        __syncthreads();
        int excl = (s - tot) + wsum[wid] + s_carry;
        if (i < n4) {
            int4 ex;
            ex.x = excl;
            ex.y = excl + t0;
            ex.z = excl + t1;
            ex.w = excl + t2;
            int4 c0 = ex;
            int4 c1; c1.x = c0.x + a0.x; c1.y = c0.y + a0.y; c1.z = c0.z + a0.z; c1.w = c0.w + a0.w;
            int4 c2; c2.x = c1.x + a1.x; c2.y = c1.y + a1.y; c2.z = c1.z + a1.z; c2.w = c1.w + a1.w;
            int4 c3; c3.x = c2.x + a2.x; c3.y = c2.y + a2.y; c3.z = c2.z + a2.z; c3.w = c2.w + a2.w;
            ((int4*)cursor4)[i] = c0;
            ((int4*)cursor4)[n4 + i] = c1;
            ((int4*)cursor4)[2 * n4 + i] = c2;
            ((int4*)cursor4)[3 * n4 + i] = c3;
        }
        __syncthreads();
        if (tid == 1023) s_carry = excl + tot;
        __syncthreads();
    }
}

__global__ void scatter_kernel(const int* __restrict__ ei, int* __restrict__ cursor,
                               int* __restrict__ eid) {
    int e = blockIdx.x * 256 + threadIdx.x;
    if (e >= N_EDGES) return;
    int d = ei[N_EDGES + e];
    int pos = atomicAdd(&cursor[d], 1);
    eid[pos] = e;
}

// ---- fused prep 2: scatter (4-shadow) | zero agg+dxb | P/Q precompute ----
__global__ __launch_bounds__(256, 4)
void fused_prep2(const int* __restrict__ ei, int* __restrict__ cursor4,
                 int* __restrict__ eid,
                 const short* __restrict__ h_bf, const short* __restrict__ pWe1,
                 const float* __restrict__ be1,
                 unsigned* __restrict__ Pu, unsigned* __restrict__ Qu,
                 float4* __restrict__ zbase) {
    __shared__ __align__(16) short sA[2 * 2048];
    const int bid = blockIdx.x, tid = threadIdx.x;
    if (bid < 3125) {                        // scatter, shadow k = e&3
        int e = bid * 256 + tid;
        int d = ei[N_EDGES + e];
        int pos = atomicAdd(&cursor4[(tid & 3) * N_NODES + d], 1);
        eid[pos] = e;
        return;
    }
    if (bid < 4725) {                        // zero agg|dxb (contiguous)
        size_t base = (size_t)(bid - 3125) * 1024 + (size_t)tid * 4;
#pragma unroll
        for (int k = 0; k < 4; ++k) {
            size_t i = base + k;
            if (i < ZERO_F4) zbase[i] = make_float4(0.f, 0.f, 0.f, 0.f);
        }
        return;
    }
    // ---- P/Q part ----
    const int lane = tid & 63;
    const int w = tid >> 6;
    const int lc = lane & 15;
    const int quad = lane >> 4;
    const int n0 = (bid - 4725) * 64;

#define STAGE_PQ(kc_, buf_) do {                                             \
        const int ko = (kc_) * 32 + (lane & 3) * 8;                          \
        const int row = w * 16 + (lane >> 2);                                \
        const int n = (n0 + row < N_NODES) ? n0 + row : N_NODES - 1;         \
        gl_lds16(h_bf + (size_t)n * 128 + ko, &sA[(buf_) * 2048 + w * 512]); \
    } while (0)

    STAGE_PQ(0, 0);
    const int ct0 = 2 * w, ct1 = 2 * w + 1;
    const int c0 = ct0 * 16 + lc, c1 = c0 + 16;

    floatx4 aP[4][2], aQ[4][2];
#pragma unroll
    for (int rt = 0; rt < 4; ++rt)
#pragma unroll
        for (int ct = 0; ct < 2; ++ct)
#pragma unroll
            for (int r = 0; r < 4; ++r) { aP[rt][ct][r] = 0.0f; aQ[rt][ct][r] = 0.0f; }

    for (int kc = 0; kc < 4; ++kc) {
        __syncthreads();
        if (kc < 3) STAGE_PQ(kc + 1, (kc + 1) & 1);
        const int buf = kc & 1;
        bf16x8 bp0 = *(const bf16x8*)&pWe1[((size_t)(kc * 8 + ct0) * 64 + lane) * 8];
        bf16x8 bp1 = *(const bf16x8*)&pWe1[((size_t)(kc * 8 + ct1) * 64 + lane) * 8];
        bf16x8 bq0 = *(const bf16x8*)&pWe1[((size_t)((kc + 4) * 8 + ct0) * 64 + lane) * 8];
        bf16x8 bq1 = *(const bf16x8*)&pWe1[((size_t)((kc + 4) * 8 + ct1) * 64 + lane) * 8];
        __builtin_amdgcn_s_setprio(1);
#pragma unroll
        for (int rt = 0; rt < 4; ++rt) {
            bf16x8 a = *(const bf16x8*)&sA[buf * 2048 + (rt * 16 + lc) * 32 + quad * 8];
            aP[rt][0] = __builtin_amdgcn_mfma_f32_16x16x32_bf16(a, bp0, aP[rt][0], 0, 0, 0);
            aP[rt][1] = __builtin_amdgcn_mfma_f32_16x16x32_bf16(a, bp1, aP[rt][1], 0, 0, 0);
            aQ[rt][0] = __builtin_amdgcn_mfma_f32_16x16x32_bf16(a, bq0, aQ[rt][0], 0, 0, 0);
            aQ[rt][1] = __builtin_amdgcn_mfma_f32_16x16x32_bf16(a, bq1, aQ[rt][1], 0, 0, 0);
        }
        __builtin_amdgcn_s_setprio(0);
    }
    float bb0 = be1[c0], bb1 = be1[c1];
    const int jid = w * 16 + lc;
#pragma unroll
    for (int rt = 0; rt < 4; ++rt)
#pragma unroll
        for (int r = 0; r < 4; ++r) {
            int n = n0 + rt * 16 + quad * 4 + r;
            if (n < N_NODES) {
                Pu[(size_t)n * 64 + jid] = cvt_pk_bf16(aP[rt][0][r] + bb0, aP[rt][1][r] + bb1);
                Qu[(size_t)n * 64 + jid] = cvt_pk_bf16(aQ[rt][0][r], aQ[rt][1][r]);
            }
        }
#undef STAGE_PQ
}

// ==================== PRIMARY edge kernel (P/Q path, 96-edge tile) ====================
// LDS 26880 B -> 6 blocks/CU (vs 4 at 128-tile). Last block pads 64 rows to a
// scratch dst row (N_NODES); agg/dxb carry one extra never-read row.
__global__ __launch_bounds__(256, 6)
void egnn_edge_pq(const unsigned* __restrict__ Pu, const unsigned* __restrict__ Qu,
                  const float* __restrict__ x,
                  const int* __restrict__ ei, const float* __restrict__ ea,
                  const int* __restrict__ eid_sorted,
                  const short* __restrict__ pWe1, const short* __restrict__ pWe2,
                  const short* __restrict__ pWx1,
                  const float* __restrict__ be2,
                  const float* __restrict__ bx1, const float* __restrict__ Wx2,
                  const float* __restrict__ bx2,
                  float* __restrict__ agg, float* __restrict__ dxb) {
    __shared__ __align__(16) short sT[EB * 128];
    __shared__ __align__(16) int s_src[EB];
    __shared__ __align__(16) int s_dst[EB];
    __shared__ float s_dir[EB * 3], sGate[EB];

    const int tid = threadIdx.x;
    const int lane = tid & 63;
    const int w = tid >> 6;
    const int lc = lane & 15;
    const int quad = lane >> 4;

    // bijective XCD swizzle for 8334 = 8*1041 + 6 workgroups (m204 form)
    int bix = blockIdx.x;
    int xcd = bix & 7, kk = bix >> 3;
    int bid = (xcd < 6 ? xcd * 1042 : 6252 + (xcd - 6) * 1041) + kk;
    const int e0 = bid * EB;

    // preamble: indices, dist, dir (rows >= N_EDGES pad to scratch dst)
    int e_reg = 0; float dist_reg = 0.0f;
    if (tid < EB) {
        int ee = e0 + tid;
        bool real = ee < N_EDGES;
        e_reg = real ? eid_sorted[ee] : 0;
        int s = ei[e_reg];
        int d = real ? ei[N_EDGES + e_reg] : N_NODES;
        s_src[tid] = s; s_dst[tid] = d;
        int di = real ? d : 0;
        float ddx = x[di * 3 + 0] - x[s * 3 + 0];
        float ddy = x[di * 3 + 1] - x[s * 3 + 1];
        float ddz = x[di * 3 + 2] - x[s * 3 + 2];
        float dot = ddx * ddx + ddy * ddy + ddz * ddz;
        dist_reg = sqrtf(dot + 1e-9f);
        float inv = fast_rcp(sqrtf(dot) + 1e-9f);
        s_dir[tid * 3 + 0] = ddx * inv;
        s_dir[tid * 3 + 1] = ddy * inv;
        s_dir[tid * 3 + 2] = ddz * inv;
        sGate[tid] = 0.0f;
    }
    __syncthreads();   // (A) src/dst visible

    // stage the ea|dist K=32 chunk into sT[0..3072)
    if (tid < EB) {
        const float4* p = (const float4*)&ea[(size_t)e_reg * 16];
        float4 a = p[0], b = p[1], c = p[2], d = p[3];
        uint4* dst = (uint4*)&sT[tid * 32];
        dst[0] = make_uint4(cvt_pk_bf16(a.x, a.y), cvt_pk_bf16(a.z, a.w),
                            cvt_pk_bf16(b.x, b.y), cvt_pk_bf16(b.z, b.w));
        dst[1] = make_uint4(cvt_pk_bf16(c.x, c.y), cvt_pk_bf16(c.z, c.w),
                            cvt_pk_bf16(d.x, d.y), cvt_pk_bf16(d.z, d.w));
        dst[2] = make_uint4(cvt_pk_bf16(dist_reg, 0.0f), 0u, 0u, 0u);
        dst[3] = make_uint4(0u, 0u, 0u, 0u);
    }

    const int ct0 = 2 * w, ct1 = 2 * w + 1;
    const int c0 = ct0 * 16 + lc, c1 = c0 + 16;
    // paired-storage write coords for this lane
    const int jblk = w * 4 + (lc >> 2);
    const int joff = (lc & 3) * 2;

    // C-init: acc = P[src] + Q[dst]
    const unsigned jb = (unsigned)(w * 64 + lc * 4);   // byte offset within row
    floatx4 acc[6][2];
#pragma unroll
    for (int rt = 0; rt < 6; ++rt) {
        int4 ss = *(const int4*)&s_src[rt * 16 + quad * 4];
        int4 dd = *(const int4*)&s_dst[rt * 16 + quad * 4];
        unsigned p0 = *(const unsigned*)((const char*)Pu + ((unsigned)ss.x * 256u + jb));
        unsigned q0 = *(const unsigned*)((const char*)Qu + ((unsigned)dd.x * 256u + jb));
        unsigned p1 = *(const unsigned*)((const char*)Pu + ((unsigned)ss.y * 256u + jb));
        unsigned q1 = *(const unsigned*)((const char*)Qu + ((unsigned)dd.y * 256u + jb));
        unsigned p2 = *(const unsigned*)((const char*)Pu + ((unsigned)ss.z * 256u + jb));
        unsigned q2 = *(const unsigned*)((const char*)Qu + ((unsigned)dd.z * 256u + jb));
        unsigned p3 = *(const unsigned*)((const char*)Pu + ((unsigned)ss.w * 256u + jb));
        unsigned q3 = *(const unsigned*)((const char*)Qu + ((unsigned)dd.w * 256u + jb));
        acc[rt][0][0] = bflo(p0) + bflo(q0);
        acc[rt][1][0] = bfhi(p0) + bfhi(q0);
        acc[rt][0][1] = bflo(p1) + bflo(q1);
        acc[rt][1][1] = bfhi(p1) + bfhi(q1);
        acc[rt][0][2] = bflo(p2) + bflo(q2);
        acc[rt][1][2] = bfhi(p2) + bfhi(q2);
        acc[rt][0][3] = bflo(p3) + bflo(q3);
        acc[rt][1][3] = bfhi(p3) + bfhi(q3);
    }
    __syncthreads();   // (B) ea chunk staged

    // layer-1 remainder: single K=32 MFMA chunk (We1 rows 256..287 = chunk 8)
    {
        bf16x8 b0 = *(const bf16x8*)&pWe1[((size_t)(8 * 8 + ct0) * 64 + lane) * 8];
        bf16x8 b1 = *(const bf16x8*)&pWe1[((size_t)(8 * 8 + ct1) * 64 + lane) * 8];
        __builtin_amdgcn_s_setprio(1);
#pragma unroll
        for (int rt = 0; rt < 6; ++rt) {
            bf16x8 a = *(const bf16x8*)&sT[(rt * 16 + lc) * 32 + quad * 8];
            acc[rt][0] = __builtin_amdgcn_mfma_f32_16x16x32_bf16(a, b0, acc[rt][0], 0, 0, 0);
            acc[rt][1] = __builtin_amdgcn_mfma_f32_16x16x32_bf16(a, b1, acc[rt][1], 0, 0, 0);
        }
        __builtin_amdgcn_s_setprio(0);
    }
    __syncthreads();

    // epilogue 1: silu -> sT (bf16, permuted-paired, swizzled)
#pragma unroll
    for (int rt = 0; rt < 6; ++rt)
#pragma unroll
        for (int r = 0; r < 4; ++r) {
            int row = rt * 16 + quad * 4 + r;
            unsigned pk = cvt_pk_bf16(silu_f(acc[rt][0][r]), silu_f(acc[rt][1][r]));
            *(unsigned*)&sT[row * 128 + (jblk ^ ((row >> 1) & 7)) * 8 + joff] = pk;
        }
    __syncthreads();

    // ---- phi_e layer 2: m = t1 @ We2 + be2 (We2 K-rows permuted in pack) ----
#pragma unroll
    for (int rt = 0; rt < 6; ++rt)
#pragma unroll
        for (int ct = 0; ct < 2; ++ct)
#pragma unroll
            for (int r = 0; r < 4; ++r) acc[rt][ct][r] = 0.0f;

    for (int kc = 0; kc < 4; ++kc) {
        bf16x8 b0 = *(const bf16x8*)&pWe2[((size_t)(kc * 8 + ct0) * 64 + lane) * 8];
        bf16x8 b1 = *(const bf16x8*)&pWe2[((size_t)(kc * 8 + ct1) * 64 + lane) * 8];
        __builtin_amdgcn_s_setprio(1);
#pragma unroll
        for (int rt = 0; rt < 6; ++rt) {
            int kb = (kc * 4 + quad) ^ ((lc >> 1) & 7);
            bf16x8 a = *(const bf16x8*)&sT[(rt * 16 + lc) * 128 + kb * 8];
            acc[rt][0] = __builtin_amdgcn_mfma_f32_16x16x32_bf16(a, b0, acc[rt][0], 0, 0, 0);
            acc[rt][1] = __builtin_amdgcn_mfma_f32_16x16x32_bf16(a, b1, acc[rt][1], 0, 0, 0);
        }
        __builtin_amdgcn_s_setprio(0);
    }
    __syncthreads();

    // write m -> sT (bias folded; permuted-paired)
    {
        float bb0 = be2[c0], bb1 = be2[c1];
#pragma unroll
        for (int rt = 0; rt < 6; ++rt)
#pragma unroll
            for (int r = 0; r < 4; ++r) {
                int row = rt * 16 + quad * 4 + r;
                unsigned pk = cvt_pk_bf16(acc[rt][0][r] + bb0, acc[rt][1][r] + bb1);
                *(unsigned*)&sT[row * 128 + (jblk ^ ((row >> 1) & 7)) * 8 + joff] = pk;
            }
    }
    __syncthreads();

    // ---- phi_x (Wx1 K-rows permuted in pack) ----
#pragma unroll
    for (int rt = 0; rt < 6; ++rt)
#pragma unroll
        for (int ct = 0; ct < 2; ++ct)
#pragma unroll
            for (int r = 0; r < 4; ++r) acc[rt][ct][r] = 0.0f;

    for (int kc = 0; kc < 4; ++kc) {
        bf16x8 b0 = *(const bf16x8*)&pWx1[((size_t)(kc * 8 + ct0) * 64 + lane) * 8];
        bf16x8 b1 = *(const bf16x8*)&pWx1[((size_t)(kc * 8 + ct1) * 64 + lane) * 8];
        __builtin_amdgcn_s_setprio(1);
#pragma unroll
        for (int rt = 0; rt < 6; ++rt) {
            int kb = (kc * 4 + quad) ^ ((lc >> 1) & 7);
            bf16x8 a = *(const bf16x8*)&sT[(rt * 16 + lc) * 128 + kb * 8];
            acc[rt][0] = __builtin_amdgcn_mfma_f32_16x16x32_bf16(a, b0, acc[rt][0], 0, 0, 0);
            acc[rt][1] = __builtin_amdgcn_mfma_f32_16x16x32_bf16(a, b1, acc[rt][1], 0, 0, 0);
        }
        __builtin_amdgcn_s_setprio(0);
    }

    // segmented agg scatter: paired column-walk (2 cols per thread, 24 rows)
    {
        const int sp = tid & 63;          // storage pair id
        const int rq = tid >> 6;          // row quarter
        const int cLo = ((sp >> 4) << 5) + (sp & 15);
        const int cHi = cLo + 16;
        const int pblk = sp >> 2;
        const int poff = (sp & 3) * 2;
        const int rb = rq * 24;
        float run0 = 0.0f, run1 = 0.0f;
        int cur = s_dst[rb];
#pragma unroll 8
        for (int r = rb; r < rb + 24; ++r) {
            int d = s_dst[r];
            if (d != cur) {
                atomicAdd(&agg[(size_t)cur * HDIM + cLo], run0);
                atomicAdd(&agg[(size_t)cur * HDIM + cHi], run1);
                run0 = 0.0f; run1 = 0.0f; cur = d;
            }
            unsigned v = *(const unsigned*)&sT[r * 128 + (pblk ^ ((r >> 1) & 7)) * 8 + poff];
            run0 += bflo(v); run1 += bfhi(v);
        }
        atomicAdd(&agg[(size_t)cur * HDIM + cLo], run0);
        atomicAdd(&agg[(size_t)cur * HDIM + cHi], run1);
    }

    // gate epilogue
    {
        float wx0 = Wx2[c0], wx1 = Wx2[c1];
        float bb0 = bx1[c0], bb1 = bx1[c1];
        float gp[6][4];
#pragma unroll
        for (int rt = 0; rt < 6; ++rt)
#pragma unroll
            for (int r = 0; r < 4; ++r)
                gp[rt][r] = silu_f(acc[rt][0][r] + bb0) * wx0 +
                            silu_f(acc[rt][1][r] + bb1) * wx1;
#pragma unroll
        for (int m = 1; m < 16; m <<= 1)
#pragma unroll
            for (int rt = 0; rt < 6; ++rt)
#pragma unroll
                for (int r = 0; r < 4; ++r)
                    gp[rt][r] += __shfl_xor(gp[rt][r], m, 64);
        if (lc == 0) {
#pragma unroll
            for (int rt = 0; rt < 6; ++rt)
#pragma unroll
                for (int r = 0; r < 4; ++r)
                    atomicAdd(&sGate[rt * 16 + quad * 4 + r], gp[rt][r]);
        }
    }
    __syncthreads();

    // segmented dx scatter: 12 chains of 8 rows x 3 components
    if (tid < 36) {
        const int comp = tid % 3;
        const int ch = tid / 3;
        const float b2 = bx2[0];
        int r = ch * 8;
        float run = 0.0f;
        int cur = s_dst[r];
        for (int k = 0; k < 8; ++k, ++r) {
            int d = s_dst[r];
            if (d != cur) {
                atomicAdd(&dxb[(size_t)cur * 3 + comp], run);
                run = 0.0f; cur = d;
            }
            run += s_dir[r * 3 + comp] * (sGate[r] + b2);
        }
        atomicAdd(&dxb[(size_t)cur * 3 + comp], run);
    }
}

// ==================== FALLBACK edge kernel (128-tile, unchanged) ====================
__global__ __launch_bounds__(256, 4)
void egnn_edge_v4(const short* __restrict__ h_bf, const float* __restrict__ x,
                  const int* __restrict__ ei, const float* __restrict__ ea,
                  const int* __restrict__ eid_sorted,
                  const short* __restrict__ pWe1, const short* __restrict__ pWe2,
                  const short* __restrict__ pWx1,
                  const float* __restrict__ be1, const float* __restrict__ be2,
                  const float* __restrict__ bx1, const float* __restrict__ Wx2,
                  const float* __restrict__ bx2,
                  float* __restrict__ agg, float* __restrict__ dxb) {
    __shared__ __align__(16) short sT[128 * 128];
    __shared__ int s_dst[128], s_eid[128];
    __shared__ float s_dist[128], s_dir[384], sGate[128];

    const int tid = threadIdx.x;
    const int lane = tid & 63;
    const int w = tid >> 6;
    const int lc = lane & 15;
    const int quad = lane >> 4;

    int bix = blockIdx.x;
    int bid = (bix < 6248) ? (bix & 7) * 781 + (bix >> 3) : bix;
    const int e0 = bid * 128;

    const int part = lane & 3;
    const int r0 = w * 32 + (lane >> 2);
    const int r1 = r0 + 16;
    const int eS0 = eid_sorted[e0 + r0], eS1 = eid_sorted[e0 + r1];
    const int es0 = ei[eS0], ed0 = ei[N_EDGES + eS0];
    const int es1 = ei[eS1], ed1 = ei[N_EDGES + eS1];

#define STAGE_H(kc_, buf_) do {                                              \
        const int ss = ((kc_) < 4);                                          \
        const int ko = ((kc_) & 3) * 32 + part * 8;                          \
        gl_lds16(h_bf + (size_t)(ss ? es0 : ed0) * 128 + ko,                 \
                 &sT[(buf_) * 4096 + w * 1024]);                             \
        gl_lds16(h_bf + (size_t)(ss ? es1 : ed1) * 128 + ko,                 \
                 &sT[(buf_) * 4096 + w * 1024 + 512]);                       \
    } while (0)

    STAGE_H(0, 0);

    if (tid < 128) {
        int e = eid_sorted[e0 + tid];
        s_eid[tid] = e;
        int s = ei[e], d = ei[N_EDGES + e];
        s_dst[tid] = d;
        float ddx = x[d * 3 + 0] - x[s * 3 + 0];
        float ddy = x[d * 3 + 1] - x[s * 3 + 1];
        float ddz = x[d * 3 + 2] - x[s * 3 + 2];
        float dot = ddx * ddx + ddy * ddy + ddz * ddz;
        s_dist[tid] = sqrtf(dot + 1e-9f);
        float inv = fast_rcp(sqrtf(dot) + 1e-9f);
        s_dir[tid * 3 + 0] = ddx * inv;
        s_dir[tid * 3 + 1] = ddy * inv;
        s_dir[tid * 3 + 2] = ddz * inv;
        sGate[tid] = 0.0f;
    }

    const int ct0 = 2 * w, ct1 = 2 * w + 1;
    const int c0 = ct0 * 16 + lc, c1 = c0 + 16;
    const int jblk = w * 4 + (lc >> 2);
    const int joff = (lc & 3) * 2;

    floatx4 acc[8][2];
#pragma unroll
    for (int rt = 0; rt < 8; ++rt)
#pragma unroll
        for (int ct = 0; ct < 2; ++ct)
#pragma unroll
            for (int r = 0; r < 4; ++r) acc[rt][ct][r] = 0.0f;

    for (int kc = 0; kc < 9; ++kc) {
        __syncthreads();
        if (kc < 7) {
            STAGE_H(kc + 1, (kc + 1) & 1);
        } else if (kc == 7) {
            if (tid < 128) {
                const float4* p = (const float4*)&ea[(size_t)s_eid[tid] * 16];
                float4 a = p[0], b = p[1], c = p[2], d = p[3];
                uint4* dst = (uint4*)&sT[0 * 4096 + tid * 32];
                dst[0] = make_uint4(cvt_pk_bf16(a.x, a.y), cvt_pk_bf16(a.z, a.w),
                                    cvt_pk_bf16(b.x, b.y), cvt_pk_bf16(b.z, b.w));
                dst[1] = make_uint4(cvt_pk_bf16(c.x, c.y), cvt_pk_bf16(c.z, c.w),
                                    cvt_pk_bf16(d.x, d.y), cvt_pk_bf16(d.z, d.w));
                dst[2] = make_uint4(cvt_pk_bf16(s_dist[tid], 0.0f), 0u, 0u, 0u);
                dst[3] = make_uint4(0u, 0u, 0u, 0u);
            }
        }
        const int buf = kc & 1;
        bf16x8 b0 = *(const bf16x8*)&pWe1[((size_t)(kc * 8 + ct0) * 64 + lane) * 8];
        bf16x8 b1 = *(const bf16x8*)&pWe1[((size_t)(kc * 8 + ct1) * 64 + lane) * 8];
#pragma unroll
        for (int rt = 0; rt < 8; ++rt) {
            bf16x8 a = *(const bf16x8*)&sT[buf * 4096 + (rt * 16 + lc) * 32 + quad * 8];
            acc[rt][0] = __builtin_amdgcn_mfma_f32_16x16x32_bf16(a, b0, acc[rt][0], 0, 0, 0);
            acc[rt][1] = __builtin_amdgcn_mfma_f32_16x16x32_bf16(a, b1, acc[rt][1], 0, 0, 0);
        }
    }
    __syncthreads();

    {
        float bb0 = be1[c0], bb1 = be1[c1];
#pragma unroll
        for (int rt = 0; rt < 8; ++rt)
#pragma unroll
            for (int r = 0; r < 4; ++r) {
                int row = rt * 16 + quad * 4 + r;
                unsigned pk = cvt_pk_bf16(silu_f(acc[rt][0][r] + bb0),
                                          silu_f(acc[rt][1][r] + bb1));
                *(unsigned*)&sT[row * 128 + (jblk ^ ((row >> 1) & 7)) * 8 + joff] = pk;
            }
    }
    __syncthreads();

#pragma unroll
    for (int rt = 0; rt < 8; ++rt)
#pragma unroll
        for (int ct = 0; ct < 2; ++ct)
#pragma unroll
            for (int r = 0; r < 4; ++r) acc[rt][ct][r] = 0.0f;

    for (int kc = 0; kc < 4; ++kc) {
        bf16x8 b0 = *(const bf16x8*)&pWe2[((size_t)(kc * 8 + ct0) * 64 + lane) * 8];
        bf16x8 b1 = *(const bf16x8*)&pWe2[((size_t)(kc * 8 + ct1) * 64 + lane) * 8];
#pragma unroll
        for (int rt = 0; rt < 8; ++rt) {
            int kb = (kc * 4 + quad) ^ ((lc >> 1) & 7);
            bf16x8 a = *(const bf16x8*)&sT[(rt * 16 + lc) * 128 + kb * 8];
            acc[rt][0] = __builtin_amdgcn_mfma_f32_16x16x32_bf16(a, b0, acc[rt][0], 0, 0, 0);
            acc[rt][1] = __builtin_amdgcn_mfma_f32_16x16x32_bf16(a, b1, acc[rt][1], 0, 0, 0);
        }
    }
    __syncthreads();

    {
        float bb0 = be2[c0], bb1 = be2[c1];
#pragma unroll
        for (int rt = 0; rt < 8; ++rt)
#pragma unroll
            for (int r = 0; r < 4; ++r) {
                int row = rt * 16 + quad * 4 + r;
                unsigned pk = cvt_pk_bf16(acc[rt][0][r] + bb0, acc[rt][1][r] + bb1);
                *(unsigned*)&sT[row * 128 + (jblk ^ ((row >> 1) & 7)) * 8 + joff] = pk;
            }
    }
    __syncthreads();

#pragma unroll
    for (int rt = 0; rt < 8; ++rt)
#pragma unroll
        for (int ct = 0; ct < 2; ++ct)
#pragma unroll
            for (int r = 0; r < 4; ++r) acc[rt][ct][r] = 0.0f;

    for (int kc = 0; kc < 4; ++kc) {
        bf16x8 b0 = *(const bf16x8*)&pWx1[((size_t)(kc * 8 + ct0) * 64 + lane) * 8];
        bf16x8 b1 = *(const bf16x8*)&pWx1[((size_t)(kc * 8 + ct1) * 64 + lane) * 8];
#pragma unroll
        for (int rt = 0; rt < 8; ++rt) {
            int kb = (kc * 4 + quad) ^ ((lc >> 1) & 7);
            bf16x8 a = *(const bf16x8*)&sT[(rt * 16 + lc) * 128 + kb * 8];
            acc[rt][0] = __builtin_amdgcn_mfma_f32_16x16x32_bf16(a, b0, acc[rt][0], 0, 0, 0);
            acc[rt][1] = __builtin_amdgcn_mfma_f32_16x16x32_bf16(a, b1, acc[rt][1], 0, 0, 0);
        }
    }

    {
        const int sp = tid & 63;
        const int rq = tid >> 6;
        const int cLo = ((sp >> 4) << 5) + (sp & 15);
        const int cHi = cLo + 16;
        const int pblk = sp >> 2;
        const int poff = (sp & 3) * 2;
        const int rb = rq * 32;
        float run0 = 0.0f, run1 = 0.0f;
        int cur = s_dst[rb];
#pragma unroll 8
        for (int r = rb; r < rb + 32; ++r) {
            int d = s_dst[r];
            if (d != cur) {
                atomicAdd(&agg[(size_t)cur * HDIM + cLo], run0);
                atomicAdd(&agg[(size_t)cur * HDIM + cHi], run1);
                run0 = 0.0f; run1 = 0.0f; cur = d;
            }
            unsigned v = *(const unsigned*)&sT[r * 128 + (pblk ^ ((r >> 1) & 7)) * 8 + poff];
            run0 += bflo(v); run1 += bfhi(v);
        }
        atomicAdd(&agg[(size_t)cur * HDIM + cLo], run0);
        atomicAdd(&agg[(size_t)cur * HDIM + cHi], run1);
    }

    {
        float wx0 = Wx2[c0], wx1 = Wx2[c1];
        float bb0 = bx1[c0], bb1 = bx1[c1];
        float gp[8][4];
#pragma unroll
        for (int rt = 0; rt < 8; ++rt)
#pragma unroll
            for (int r = 0; r < 4; ++r)
                gp[rt][r] = silu_f(acc[rt][0][r] + bb0) * wx0 +
                            silu_f(acc[rt][1][r] + bb1) * wx1;
#pragma unroll
        for (int m = 1; m < 16; m <<= 1)
#pragma unroll
            for (int rt = 0; rt < 8; ++rt)
#pragma unroll
                for (int r = 0; r < 4; ++r)
                    gp[rt][r] += __shfl_xor(gp[rt][r], m, 64);
        if (lc == 0) {
#pragma unroll
            for (int rt = 0; rt < 8; ++rt)
#pragma unroll
                for (int r = 0; r < 4; ++r)
                    atomicAdd(&sGate[rt * 16 + quad * 4 + r], gp[rt][r]);
        }
    }
    __syncthreads();

    if (tid < 48) {
        const int comp = tid % 3;
        const int ch = tid / 3;
        const float b2 = bx2[0];
        int r = ch * 8;
        float run = 0.0f;
        int cur = s_dst[r];
        for (int k = 0; k < 8; ++k, ++r) {
            int d = s_dst[r];
            if (d != cur) {
                atomicAdd(&dxb[(size_t)cur * 3 + comp], run);
                run = 0.0f; cur = d;
            }
            run += s_dir[r * 3 + comp] * (sGate[r] + b2);
        }
        atomicAdd(&dxb[(size_t)cur * 3 + comp], run);
    }
#undef STAGE_H
}

__global__ __launch_bounds__(256, 4)
void egnn_node_mfma(const short* __restrict__ h_bf, const float* __restrict__ h,
                    const float* __restrict__ x,
                    const float* __restrict__ agg, const float* __restrict__ dxb,
                    const short* __restrict__ pWh1, const short* __restrict__ pWh2,
                    const float* __restrict__ bh1, const float* __restrict__ bh2,
                    const float* __restrict__ ln_g, const float* __restrict__ ln_b,
                    float* __restrict__ hout, float* __restrict__ xout) {
    __shared__ __align__(16) short sT[64 * 128];
    __shared__ float sS1[64], sS2[64];

    const int tid = threadIdx.x;
    const int lane = tid & 63;
    const int w = tid >> 6;
    const int lc = lane & 15;
    const int quad = lane >> 4;
    const int n0 = blockIdx.x * 64;

#define STAGE_N(kc_, buf_) do {                                              \
        if ((kc_) < 4) {                                                     \
            const int ko = (kc_) * 32 + (lane & 3) * 8;                      \
            const int row = w * 16 + (lane >> 2);                            \
            const int n = (n0 + row < N_NODES) ? n0 + row : N_NODES - 1;     \
            gl_lds16(h_bf + (size_t)n * 128 + ko,                            \
                     &sT[(buf_) * 2048 + w * 512]);                          \
        } else {                                                             \
            const int srow = tid >> 2, prt = tid & 3;                        \
            const int n = (n0 + srow < N_NODES) ? n0 + srow : N_NODES - 1;   \
            const float4* p = (const float4*)&agg[(size_t)n * HDIM +         \
                                                  ((kc_) & 3) * 32 + prt * 8]; \
            float4 a = p[0], b = p[1];                                       \
            *(uint4*)&sT[(buf_) * 2048 + srow * 32 + prt * 8] =              \
                make_uint4(cvt_pk_bf16(a.x, a.y), cvt_pk_bf16(a.z, a.w),     \
                           cvt_pk_bf16(b.x, b.y), cvt_pk_bf16(b.z, b.w));    \
        }                                                                    \
    } while (0)

    STAGE_N(0, 0);
    if (tid < 64) { sS1[tid] = 0.0f; sS2[tid] = 0.0f; }

    const int ct0 = 2 * w, ct1 = 2 * w + 1;
    const int c0 = ct0 * 16 + lc, c1 = c0 + 16;
    const int jblk = w * 4 + (lc >> 2);
    const int joff = (lc & 3) * 2;

    floatx4 acc[4][2];
#pragma unroll
    for (int rt = 0; rt < 4; ++rt)
#pragma unroll
        for (int ct = 0; ct < 2; ++ct)
#pragma unroll
            for (int r = 0; r < 4; ++r) acc[rt][ct][r] = 0.0f;

    for (int kc = 0; kc < 8; ++kc) {
        __syncthreads();
        if (kc < 7) STAGE_N(kc + 1, (kc + 1) & 1);
        const int buf = kc & 1;
        bf16x8 b0 = *(const bf16x8*)&pWh1[((size_t)(kc * 8 + ct0) * 64 + lane) * 8];
        bf16x8 b1 = *(const bf16x8*)&pWh1[((size_t)(kc * 8 + ct1) * 64 + lane) * 8];
        __builtin_amdgcn_s_setprio(1);
#pragma unroll
        for (int rt = 0; rt < 4; ++rt) {
            bf16x8 a = *(const bf16x8*)&sT[buf * 2048 + (rt * 16 + lc) * 32 + quad * 8];
            acc[rt][0] = __builtin_amdgcn_mfma_f32_16x16x32_bf16(a, b0, acc[rt][0], 0, 0, 0);
            acc[rt][1] = __builtin_amdgcn_mfma_f32_16x16x32_bf16(a, b1, acc[rt][1], 0, 0, 0);
        }
        __builtin_amdgcn_s_setprio(0);
    }
    __syncthreads();

    {
        float bb0 = bh1[c0], bb1 = bh1[c1];
#pragma unroll
        for (int rt = 0; rt < 4; ++rt)
#pragma unroll
            for (int r = 0; r < 4; ++r) {
                int row = rt * 16 + quad * 4 + r;
                unsigned pk = cvt_pk_bf16(silu_f(acc[rt][0][r] + bb0),
                                          silu_f(acc[rt][1][r] + bb1));
                *(unsigned*)&sT[row * 128 + (jblk ^ ((row >> 1) & 7)) * 8 + joff] = pk;
            }
    }
    __syncthreads();

#pragma unroll
    for (int rt = 0; rt < 4; ++rt)
#pragma unroll
        for (int ct = 0; ct < 2; ++ct)
#pragma unroll
            for (int r = 0; r < 4; ++r) acc[rt][ct][r] = 0.0f;

    for (int kc = 0; kc < 4; ++kc) {
        bf16x8 b0 = *(const bf16x8*)&pWh2[((size_t)(kc * 8 + ct0) * 64 + lane) * 8];
        bf16x8 b1 = *(const bf16x8*)&pWh2[((size_t)(kc * 8 + ct1) * 64 + lane) * 8];
        __builtin_amdgcn_s_setprio(1);
#pragma unroll
        for (int rt = 0; rt < 4; ++rt) {
            int kb = (kc * 4 + quad) ^ ((lc >> 1) & 7);
            bf16x8 a = *(const bf16x8*)&sT[(rt * 16 + lc) * 128 + kb * 8];
            acc[rt][0] = __builtin_amdgcn_mfma_f32_16x16x32_bf16(a, b0, acc[rt][0], 0, 0, 0);
            acc[rt][1] = __builtin_amdgcn_mfma_f32_16x16x32_bf16(a, b1, acc[rt][1], 0, 0, 0);
        }
        __builtin_amdgcn_s_setprio(0);
    }

    {
        float bb0 = bh2[c0], bb1 = bh2[c1];
#pragma unroll
        for (int rt = 0; rt < 4; ++rt)
#pragma unroll
            for (int r = 0; r < 4; ++r) {
                int row = rt * 16 + quad * 4 + r;
                int n = n0 + row;
                int nc = (n < N_NODES) ? n : (N_NODES - 1);
                float v0 = acc[rt][0][r] + bb0 + h[(size_t)nc * HDIM + c0];
                float v1 = acc[rt][1][r] + bb1 + h[(size_t)nc * HDIM + c1];
                acc[rt][0][r] = v0;
                acc[rt][1][r] = v1;
                float s1 = v0 + v1;
                float s2 = v0 * v0 + v1 * v1;
#pragma unroll
                for (int m = 1; m < 16; m <<= 1) {
                    s1 += __shfl_xor(s1, m, 64);
                    s2 += __shfl_xor(s2, m, 64);
                }
                if (lc == 0) {
                    atomicAdd(&sS1[row], s1);
                    atomicAdd(&sS2[row], s2);
                }
            }
    }
    __syncthreads();
    {
        float g0 = ln_g[c0], g1 = ln_g[c1];
        float lb0 = ln_b[c0], lb1 = ln_b[c1];
#pragma unroll
        for (int rt = 0; rt < 4; ++rt)
#pragma unroll
            for (int r = 0; r < 4; ++r) {
                int row = rt * 16 + quad * 4 + r;
                int n = n0 + row;
                if (n < N_NODES) {
                    float mu = sS1[row] * (1.0f / 128.0f);
                    float var = sS2[row] * (1.0f / 128.0f) - mu * mu;
                    float rs = rsqrtf(var + 1e-5f);
                    hout[(size_t)n * HDIM + c0] = (acc[rt][0][r] - mu) * rs * g0 + lb0;
                    hout[(size_t)n * HDIM + c1] = (acc[rt][1][r] - mu) * rs * g1 + lb1;
                }
            }
    }

    if (tid < 192) {
        int n = n0 + tid / 3;
        int d = tid - (tid / 3) * 3;
        if (n < N_NODES) xout[(size_t)n * 3 + d] = x[(size_t)n * 3 + d] + dxb[(size_t)n * 3 + d];
    }
#undef STAGE_N
}

extern "C" void kernel_launch(void* const* d_in, const int* in_sizes, int n_in,
                              void* d_out, int out_size, void* d_ws, size_t ws_size,
                              hipStream_t stream) {
    (void)in_sizes; (void)n_in; (void)out_size;

    const float* h   = (const float*)d_in[0];
    const float* x   = (const float*)d_in[1];
    const int*   ei  = (const int*)d_in[2];
    const float* ea  = (const float*)d_in[3];
    const float* We1 = (const float*)d_in[4];
    const float* be1 = (const float*)d_in[5];
    const float* We2 = (const float*)d_in[6];
    const float* be2 = (const float*)d_in[7];
    const float* Wh1 = (const float*)d_in[8];
    const float* bh1 = (const float*)d_in[9];
    const float* Wh2 = (const float*)d_in[10];
    const float* bh2 = (const float*)d_in[11];
    const float* Wx1 = (const float*)d_in[12];
    const float* bx1 = (const float*)d_in[13];
    const float* Wx2 = (const float*)d_in[14];
    const float* bx2 = (const float*)d_in[15];
    const float* lng = (const float*)d_in[16];
    const float* lnb = (const float*)d_in[17];

    float* hout = (float*)d_out;
    float* xout = hout + (size_t)N_NODES * HDIM;

    const size_t CH = 8 * 64 * 8;
    const size_t oWe1 = 0, oWh1 = 17 * CH, oWh2 = 25 * CH;
    const size_t oWe2 = 9 * CH, oWx1 = 13 * CH;
    const size_t pwElems = 29 * CH;

    // +1 scratch row on agg/dxb for the ragged 96-tile padding
    const size_t aggElems = (size_t)(N_NODES + 1) * HDIM;
    const size_t aggB = aggElems * 4;                       // 25,600,512
    const size_t dxbB = (((size_t)(N_NODES + 1) * 3 * 4) + 15) & ~(size_t)15;  // 600,016
    const size_t pwB = pwElems * 2;
    const size_t hbB = (size_t)N_NODES * HDIM * 2;
    const size_t cntB = (size_t)N_NODES * 4;
    const size_t eidB = (size_t)N_EDGES * 4;

    char* ws = (char*)d_ws;
    // bigws needs 4-shadow cnt + 4-shadow cursor (8 * cntB)
    const bool bigws = ws_size >= aggB + dxbB + pwB + hbB + 8 * cntB + eidB;

    float* agg; float* dxb; short* pw; short* h_bf; int* cnt; int* cursor; int* eid;
    if (bigws) {
        agg    = (float*)ws;
        dxb    = (float*)(ws + aggB);
        pw     = (short*)(ws + aggB + dxbB);
        h_bf   = (short*)(ws + aggB + dxbB + pwB);
        cnt    = (int*)(ws + aggB + dxbB + pwB + hbB);                 // cnt4[4][N]
        cursor = (int*)(ws + aggB + dxbB + pwB + hbB + 4 * cntB);      // cursor4[4][N]
        eid    = (int*)(ws + aggB + dxbB + pwB + hbB + 8 * cntB);
    } else {
        pw     = (short*)ws;
        h_bf   = (short*)(ws + pwB);
        cnt    = (int*)(ws + pwB + hbB);
        cursor = (int*)(ws + pwB + hbB + cntB);
        eid    = (int*)(ws + pwB + hbB + 2 * cntB);
        agg    = (float*)d_out;    // aliasing safe: node blocks read their agg/
        dxb    = agg + (size_t)N_NODES * HDIM;  // fallback: no scratch row
    }

    if (bigws) {
        // P/Q live in d_out (free scratch until node kernel writes hout/xout)
        unsigned* Pu = (unsigned*)d_out;
        unsigned* Qu = Pu + (size_t)N_NODES * 64;

        hipMemsetAsync(cnt, 0, 4 * cntB, stream);
        // hist (4-shadow) | pack h | pack weights
        fused_prep1<<<6308, 256, 0, stream>>>(h, h_bf, We1, We2, Wx1, Wh1, Wh2,
                                              pw, ei, cnt);
        scan4_kernel<<<1, 1024, 0, stream>>>(cnt, cursor, N_NODES / 4);
        // scatter (4-shadow) | zero agg+dxb (contiguous) | P/Q precompute
        fused_prep2<<<5507, 256, 0, stream>>>(ei, cursor, eid, h_bf, pw + oWe1,
                                              be1, Pu, Qu, (float4*)agg);
        egnn_edge_pq<<<NWG_E, 256, 0, stream>>>(
            Pu, Qu, x, ei, ea, eid, pw + oWe1, pw + oWe2, pw + oWx1,
            be2, bx1, Wx2, bx2, agg, dxb);
    } else {
        hipMemsetAsync(agg, 0, (size_t)N_NODES * HDIM * 4, stream);
        hipMemsetAsync(dxb, 0, (size_t)N_NODES * 3 * 4, stream);
        hipMemsetAsync(cnt, 0, cntB, stream);
        pack_bf16_kernel<<<(N_NODES * HDIM / 8 + 255) / 256, 256, 0, stream>>>(
            h, h_bf, N_NODES * HDIM / 8);
        pack_all_w<<<(29 * 512 + 255) / 256, 256, 0, stream>>>(We1, We2, Wx1, Wh1, Wh2, pw);
        hist_kernel<<<(N_EDGES + 255) / 256, 256, 0, stream>>>(ei, cnt);
        scan_kernel<<<1, 1024, 0, stream>>>(cnt, cursor, N_NODES / 4);
        scatter_kernel<<<(N_EDGES + 255) / 256, 256, 0, stream>>>(ei, cursor, eid);
        egnn_edge_v4<<<N_EDGES / 128, 256, 0, stream>>>(
            h_bf, x, ei, ea, eid, pw + oWe1, pw + oWe2, pw + oWx1,
            be1, be2, bx1, Wx2, bx2, agg, dxb);
    }

    egnn_node_mfma<<<(N_NODES + 63) / 64, 256, 0, stream>>>(
        h_bf, h, x, agg, dxb, pw + oWh1, pw + oWh2,
        bh1, bh2, lng, lnb, hout, xout);
}

// Round 5
// 516.742 us; speedup vs baseline: 1.0180x; 1.0180x over previous
//
#include <hip/hip_runtime.h>
#include <math.h>

#define N_NODES 50000
#define N_EDGES 800000
#define HDIM 128
// zero region: agg (N x 128 f32) + dxb (N x 3 f32) = 6,550,000 floats = 1,637,500 float4
#define ZERO_F4 1637500

typedef __attribute__((ext_vector_type(8))) short bf16x8;
typedef __attribute__((ext_vector_type(4))) float floatx4;

__device__ __forceinline__ unsigned f2bf_u(float f) {
    union { float f; unsigned u; } x; x.f = f;
    return (x.u + 0x7FFFu + ((x.u >> 16) & 1u)) >> 16;
}
__device__ __forceinline__ short f2bf(float f) { return (short)f2bf_u(f); }
__device__ __forceinline__ float bf2f(short s) {
    union { float f; unsigned u; } x; x.u = ((unsigned)(unsigned short)s) << 16;
    return x.f;
}
// packed bf16 pair: lo = bf16(a), hi = bf16(b)  (HW RNE, 1 instr)
__device__ __forceinline__ unsigned cvt_pk_bf16(float a, float b) {
    unsigned r;
    asm("v_cvt_pk_bf16_f32 %0, %1, %2" : "=v"(r) : "v"(a), "v"(b));
    return r;
}
__device__ __forceinline__ float bflo(unsigned u) {
    union { float f; unsigned u; } x; x.u = u << 16; return x.f;
}
__device__ __forceinline__ float bfhi(unsigned u) {
    union { float f; unsigned u; } x; x.u = u & 0xffff0000u; return x.f;
}
__device__ __forceinline__ float fast_rcp(float x) {
    float r; asm("v_rcp_f32 %0, %1" : "=v"(r) : "v"(x)); return r;
}
__device__ __forceinline__ float silu_f(float v) {
    return v * fast_rcp(1.0f + __expf(-v));
}

// async 16B/lane global->LDS DMA; lds base wave-uniform, HW adds lane*16.
__device__ __forceinline__ void gl_lds16(const void* g, void* l) {
    __builtin_amdgcn_global_load_lds(
        (const __attribute__((address_space(1))) unsigned int*)g,
        (__attribute__((address_space(3))) unsigned int*)l, 16, 0, 0);
}

// Storage-column permutation: storage j holds original activation column
// p(j) = (j&~31) + ((j&31)>>1) + (j&1)*16, so a lane's (c0, c0+16) acc pair
// lands in ADJACENT shorts -> one ds_write_b32 / ds_read_b32 per pair.
// Weights consuming these activations (We2, Wx1, Wh2) have K rows permuted
// by p() in the pack; MFMA contraction is K-order-invariant.
__device__ __forceinline__ int permk(int k) {
    return (k & ~31) + ((k & 31) >> 1) + (k & 1) * 16;
}

// ---- shared bodies ----
__device__ __forceinline__ void pack_w_body(int t, const float* We1, const float* We2,
                                            const float* Wx1, const float* Wh1,
                                            const float* Wh2, short* pw) {
    int u = t >> 9;
    const float* W; int K, base; bool pk;
    if (u < 9)       { W = We1; K = 273; base = 0;  pk = false; }
    else if (u < 13) { W = We2; K = 128; base = 9;  pk = true;  }
    else if (u < 17) { W = Wx1; K = 128; base = 13; pk = true;  }
    else if (u < 25) { W = Wh1; K = 256; base = 17; pk = false; }
    else             { W = Wh2; K = 128; base = 25; pk = true;  }
    int tl = t - base * 512;
    int lane = tl & 63;
    int ctk = tl >> 6;
    int ct = ctk & 7, kc = ctk >> 3;
    int c = ct * 16 + (lane & 15);
    int kb = kc * 32 + (lane >> 4) * 8;
    bf16x8 v;
#pragma unroll
    for (int j = 0; j < 8; ++j) {
        int k = kb + j;
        int ks = pk ? permk(k) : k;
        v[j] = (k < K) ? f2bf(W[(size_t)ks * HDIM + c]) : (short)0;
    }
    *(bf16x8*)&pw[(size_t)t * 8] = v;
}

__device__ __forceinline__ void pack_h_body(int t, const float* src, short* dst) {
    const float4* p = (const float4*)(src + (size_t)t * 8);
    float4 a = p[0], b = p[1];
    uint4 o;
    o.x = cvt_pk_bf16(a.x, a.y);
    o.y = cvt_pk_bf16(a.z, a.w);
    o.z = cvt_pk_bf16(b.x, b.y);
    o.w = cvt_pk_bf16(b.z, b.w);
    *(uint4*)(dst + (size_t)t * 8) = o;
}

// ---- K1: hist (4-shadow) | pack h | pack weights | zero agg+dxb ----
// Shadow k = e&3 == tid&3 (blocks are 256 = 0 mod 4); same key in scatter.
__global__ __launch_bounds__(256)
void fused_prep1(const float* __restrict__ h, short* __restrict__ h_bf,
                 const float* __restrict__ We1, const float* __restrict__ We2,
                 const float* __restrict__ Wx1, const float* __restrict__ Wh1,
                 const float* __restrict__ Wh2, short* __restrict__ pw,
                 const int* __restrict__ ei, int* __restrict__ cnt4,
                 float4* __restrict__ zbase) {
    int bid = blockIdx.x, tid = threadIdx.x;
    if (bid < 3125) {                       // hist: 3125*256 == N_EDGES
        int e = bid * 256 + tid;
        atomicAdd(&cnt4[(tid & 3) * N_NODES + ei[N_EDGES + e]], 1);
    } else if (bid < 6250) {                // pack h: 3125*256 == N*H/8
        pack_h_body((bid - 3125) * 256 + tid, h, h_bf);
    } else if (bid < 6308) {                // pack weights
        int t = (bid - 6250) * 256 + tid;
        if (t < 29 * 512) pack_w_body(t, We1, We2, Wx1, Wh1, Wh2, pw);
    } else {                                // zero agg|dxb (contiguous)
        size_t base = (size_t)(bid - 6308) * 1024 + (size_t)tid * 4;
#pragma unroll
        for (int k = 0; k < 4; ++k) {
            size_t i = base + k;
            if (i < ZERO_F4) zbase[i] = make_float4(0.f, 0.f, 0.f, 0.f);
        }
    }
}

// ---- standalone versions (fallback path) ----
__global__ void pack_all_w(const float* __restrict__ We1, const float* __restrict__ We2,
                           const float* __restrict__ Wx1, const float* __restrict__ Wh1,
                           const float* __restrict__ Wh2, short* __restrict__ pw) {
    int t = blockIdx.x * 256 + threadIdx.x;
    if (t < 29 * 512) pack_w_body(t, We1, We2, Wx1, Wh1, Wh2, pw);
}

__global__ void pack_bf16_kernel(const float* __restrict__ src, short* __restrict__ dst,
                                 int n8) {
    int t = blockIdx.x * 256 + threadIdx.x;
    if (t < n8) pack_h_body(t, src, dst);
}

__global__ void hist_kernel(const int* __restrict__ ei, int* __restrict__ cnt) {
    int e = blockIdx.x * 256 + threadIdx.x;
    if (e < N_EDGES) atomicAdd(&cnt[ei[N_EDGES + e]], 1);
}

// int4-per-thread exclusive scan (fallback, n multiple of 4)
__global__ __launch_bounds__(1024)
void scan_kernel(const int* __restrict__ cnt, int* __restrict__ cursor, int n4) {
    __shared__ int wsum[16];
    __shared__ int s_carry;
    const int tid = threadIdx.x;
    const int lane = tid & 63, wid = tid >> 6;
    if (tid == 0) s_carry = 0;
    __syncthreads();
    for (int base = 0; base < n4; base += 1024) {
        int i = base + tid;
        int4 v = make_int4(0, 0, 0, 0);
        if (i < n4) v = ((const int4*)cnt)[i];
        int t0 = v.x, t1 = t0 + v.y, t2 = t1 + v.z, tot = t2 + v.w;
        int s = tot;
#pragma unroll
        for (int off = 1; off < 64; off <<= 1) {
            int sh = __shfl_up(s, off, 64);
            if (lane >= off) s += sh;
        }
        if (lane == 63) wsum[wid] = s;
        __syncthreads();
        if (tid < 16) {
            int t = wsum[tid];
            int sc = t;
#pragma unroll
            for (int off = 1; off < 16; off <<= 1) {
                int tt = __shfl_up(sc, off, 64);
                if (lane >= off) sc += tt;
            }
            wsum[tid] = sc - t;   // exclusive
        }
        __syncthreads();
        int excl = (s - tot) + wsum[wid] + s_carry;
        if (i < n4) {
            int4 o;
            o.x = excl; o.y = excl + t0; o.z = excl + t1; o.w = excl + t2;
            ((int4*)cursor)[i] = o;
        }
        __syncthreads();
        if (tid == 1023) s_carry = excl + tot;
        __syncthreads();
    }
}

__global__ void scatter_kernel(const int* __restrict__ ei, int* __restrict__ cursor,
                               int* __restrict__ eid) {
    int e = blockIdx.x * 256 + threadIdx.x;
    if (e >= N_EDGES) return;
    int d = ei[N_EDGES + e];
    int pos = atomicAdd(&cursor[d], 1);
    eid[pos] = e;
}

// ---- K3: 4-shadow scatter (shadow key matches hist: e&3 == tid&3) ----
__global__ void scatter4_kernel(const int* __restrict__ ei, int* __restrict__ cursor4,
                                int* __restrict__ eid) {
    int e = blockIdx.x * 256 + threadIdx.x;
    int d = ei[N_EDGES + e];
    int pos = atomicAdd(&cursor4[(threadIdx.x & 3) * N_NODES + d], 1);
    eid[pos] = e;
}

// ---- K2: scan (block 0, 2-pass, 1 barrier) | P/Q precompute (blocks 1..) ----
// cursor4[k][d] = csr_start(d) + sum_{j<k} cnt4[j][d].
// P = h @ We1[0:128] + be1, Q = h @ We1[128:256]; packed col-pair layout:
// Pu[n*64 + w*16+lc] = bf16 pair (lo = col 32w+lc, hi = +16).
__global__ __launch_bounds__(256, 4)
void scan_pq_kernel(const int* __restrict__ cnt4, int* __restrict__ cursor4,
                    const short* __restrict__ h_bf, const short* __restrict__ pWe1,
                    const float* __restrict__ be1,
                    unsigned* __restrict__ Pu, unsigned* __restrict__ Qu) {
    __shared__ __align__(16) short sA[2 * 2048];
    __shared__ int wsum[4];
    const int bid = blockIdx.x, tid = threadIdx.x;

    if (bid == 0) {
        // ---- 4-shadow exclusive scan, 256 threads, 2 passes ----
        const int n4 = N_NODES / 4;            // 12500
        const int CHK = (n4 + 255) / 256;      // 49
        int i0 = tid * CHK;
        int i1 = i0 + CHK; if (i1 > n4) i1 = n4;
        int tsum = 0;
        for (int i = i0; i < i1; ++i) {
            int4 a0 = ((const int4*)cnt4)[i];
            int4 a1 = ((const int4*)cnt4)[n4 + i];
            int4 a2 = ((const int4*)cnt4)[2 * n4 + i];
            int4 a3 = ((const int4*)cnt4)[3 * n4 + i];
            tsum += a0.x + a0.y + a0.z + a0.w + a1.x + a1.y + a1.z + a1.w +
                    a2.x + a2.y + a2.z + a2.w + a3.x + a3.y + a3.z + a3.w;
        }
        const int lane = tid & 63, wid = tid >> 6;
        int s = tsum;
#pragma unroll
        for (int off = 1; off < 64; off <<= 1) {
            int sh = __shfl_up(s, off, 64);
            if (lane >= off) s += sh;
        }
        if (lane == 63) wsum[wid] = s;
        __syncthreads();
        int wpre = 0;
#pragma unroll
        for (int j = 0; j < 4; ++j) wpre += (j < wid) ? wsum[j] : 0;
        int run = wpre + s - tsum;             // exclusive prefix
        for (int i = i0; i < i1; ++i) {
            int4 a0 = ((const int4*)cnt4)[i];
            int4 a1 = ((const int4*)cnt4)[n4 + i];
            int4 a2 = ((const int4*)cnt4)[2 * n4 + i];
            int4 a3 = ((const int4*)cnt4)[3 * n4 + i];
            int4 c0v, c1v, c2v, c3v;
            c0v.x = run;          c1v.x = c0v.x + a0.x; c2v.x = c1v.x + a1.x; c3v.x = c2v.x + a2.x;
            run = c3v.x + a3.x;
            c0v.y = run;          c1v.y = c0v.y + a0.y; c2v.y = c1v.y + a1.y; c3v.y = c2v.y + a2.y;
            run = c3v.y + a3.y;
            c0v.z = run;          c1v.z = c0v.z + a0.z; c2v.z = c1v.z + a1.z; c3v.z = c2v.z + a2.z;
            run = c3v.z + a3.z;
            c0v.w = run;          c1v.w = c0v.w + a0.w; c2v.w = c1v.w + a1.w; c3v.w = c2v.w + a2.w;
            run = c3v.w + a3.w;
            ((int4*)cursor4)[i] = c0v;
            ((int4*)cursor4)[n4 + i] = c1v;
            ((int4*)cursor4)[2 * n4 + i] = c2v;
            ((int4*)cursor4)[3 * n4 + i] = c3v;
        }
        return;
    }

    // ---- P/Q part ----
    const int lane = tid & 63;
    const int w = tid >> 6;
    const int lc = lane & 15;
    const int quad = lane >> 4;
    const int n0 = (bid - 1) * 64;

#define STAGE_PQ(kc_, buf_) do {                                             \
        const int ko = (kc_) * 32 + (lane & 3) * 8;                          \
        const int row = w * 16 + (lane >> 2);                                \
        const int n = (n0 + row < N_NODES) ? n0 + row : N_NODES - 1;         \
        gl_lds16(h_bf + (size_t)n * 128 + ko, &sA[(buf_) * 2048 + w * 512]); \
    } while (0)

    STAGE_PQ(0, 0);
    const int ct0 = 2 * w, ct1 = 2 * w + 1;
    const int c0 = ct0 * 16 + lc, c1 = c0 + 16;

    floatx4 aP[4][2], aQ[4][2];
#pragma unroll
    for (int rt = 0; rt < 4; ++rt)
#pragma unroll
        for (int ct = 0; ct < 2; ++ct)
#pragma unroll
            for (int r = 0; r < 4; ++r) { aP[rt][ct][r] = 0.0f; aQ[rt][ct][r] = 0.0f; }

    for (int kc = 0; kc < 4; ++kc) {
        __syncthreads();
        if (kc < 3) STAGE_PQ(kc + 1, (kc + 1) & 1);
        const int buf = kc & 1;
        bf16x8 bp0 = *(const bf16x8*)&pWe1[((size_t)(kc * 8 + ct0) * 64 + lane) * 8];
        bf16x8 bp1 = *(const bf16x8*)&pWe1[((size_t)(kc * 8 + ct1) * 64 + lane) * 8];
        bf16x8 bq0 = *(const bf16x8*)&pWe1[((size_t)((kc + 4) * 8 + ct0) * 64 + lane) * 8];
        bf16x8 bq1 = *(const bf16x8*)&pWe1[((size_t)((kc + 4) * 8 + ct1) * 64 + lane) * 8];
        __builtin_amdgcn_s_setprio(1);
#pragma unroll
        for (int rt = 0; rt < 4; ++rt) {
            bf16x8 a = *(const bf16x8*)&sA[buf * 2048 + (rt * 16 + lc) * 32 + quad * 8];
            aP[rt][0] = __builtin_amdgcn_mfma_f32_16x16x32_bf16(a, bp0, aP[rt][0], 0, 0, 0);
            aP[rt][1] = __builtin_amdgcn_mfma_f32_16x16x32_bf16(a, bp1, aP[rt][1], 0, 0, 0);
            aQ[rt][0] = __builtin_amdgcn_mfma_f32_16x16x32_bf16(a, bq0, aQ[rt][0], 0, 0, 0);
            aQ[rt][1] = __builtin_amdgcn_mfma_f32_16x16x32_bf16(a, bq1, aQ[rt][1], 0, 0, 0);
        }
        __builtin_amdgcn_s_setprio(0);
    }
    float bb0 = be1[c0], bb1 = be1[c1];
    const int jid = w * 16 + lc;
#pragma unroll
    for (int rt = 0; rt < 4; ++rt)
#pragma unroll
        for (int r = 0; r < 4; ++r) {
            int n = n0 + rt * 16 + quad * 4 + r;
            if (n < N_NODES) {
                Pu[(size_t)n * 64 + jid] = cvt_pk_bf16(aP[rt][0][r] + bb0, aP[rt][1][r] + bb1);
                Qu[(size_t)n * 64 + jid] = cvt_pk_bf16(aQ[rt][0][r], aQ[rt][1][r]);
            }
        }
#undef STAGE_PQ
}

// ==================== PRIMARY edge kernel (P/Q path, 128-tile, proven) ====================
__global__ __launch_bounds__(256, 4)
void egnn_edge_pq(const unsigned* __restrict__ Pu, const unsigned* __restrict__ Qu,
                  const float* __restrict__ x,
                  const int* __restrict__ ei, const float* __restrict__ ea,
                  const int* __restrict__ eid_sorted,
                  const short* __restrict__ pWe1, const short* __restrict__ pWe2,
                  const short* __restrict__ pWx1,
                  const float* __restrict__ be2,
                  const float* __restrict__ bx1, const float* __restrict__ Wx2,
                  const float* __restrict__ bx2,
                  float* __restrict__ agg, float* __restrict__ dxb) {
    __shared__ __align__(16) short sT[128 * 128];
    __shared__ __align__(16) int s_src[128];
    __shared__ __align__(16) int s_dst[128];
    __shared__ float s_dir[384], sGate[128];

    const int tid = threadIdx.x;
    const int lane = tid & 63;
    const int w = tid >> 6;
    const int lc = lane & 15;
    const int quad = lane >> 4;

    int bix = blockIdx.x;
    int bid = (bix < 6248) ? (bix & 7) * 781 + (bix >> 3) : bix;
    const int e0 = bid * 128;

    // preamble: indices, dist, dir
    int e_reg = 0; float dist_reg = 0.0f;
    if (tid < 128) {
        e_reg = eid_sorted[e0 + tid];
        int s = ei[e_reg], d = ei[N_EDGES + e_reg];
        s_src[tid] = s; s_dst[tid] = d;
        float ddx = x[d * 3 + 0] - x[s * 3 + 0];
        float ddy = x[d * 3 + 1] - x[s * 3 + 1];
        float ddz = x[d * 3 + 2] - x[s * 3 + 2];
        float dot = ddx * ddx + ddy * ddy + ddz * ddz;
        dist_reg = sqrtf(dot + 1e-9f);
        float inv = fast_rcp(sqrtf(dot) + 1e-9f);
        s_dir[tid * 3 + 0] = ddx * inv;
        s_dir[tid * 3 + 1] = ddy * inv;
        s_dir[tid * 3 + 2] = ddz * inv;
        sGate[tid] = 0.0f;
    }
    __syncthreads();   // (A) src/dst visible

    // stage the ea|dist K=32 chunk into sT[0..4096)
    if (tid < 128) {
        const float4* p = (const float4*)&ea[(size_t)e_reg * 16];
        float4 a = p[0], b = p[1], c = p[2], d = p[3];
        uint4* dst = (uint4*)&sT[tid * 32];
        dst[0] = make_uint4(cvt_pk_bf16(a.x, a.y), cvt_pk_bf16(a.z, a.w),
                            cvt_pk_bf16(b.x, b.y), cvt_pk_bf16(b.z, b.w));
        dst[1] = make_uint4(cvt_pk_bf16(c.x, c.y), cvt_pk_bf16(c.z, c.w),
                            cvt_pk_bf16(d.x, d.y), cvt_pk_bf16(d.z, d.w));
        dst[2] = make_uint4(cvt_pk_bf16(dist_reg, 0.0f), 0u, 0u, 0u);
        dst[3] = make_uint4(0u, 0u, 0u, 0u);
    }

    const int ct0 = 2 * w, ct1 = 2 * w + 1;
    const int c0 = ct0 * 16 + lc, c1 = c0 + 16;
    // paired-storage write coords for this lane
    const int jblk = w * 4 + (lc >> 2);
    const int joff = (lc & 3) * 2;

    // C-init: acc = P[src] + Q[dst]
    const unsigned jb = (unsigned)(w * 64 + lc * 4);   // byte offset within row
    floatx4 acc[8][2];
#pragma unroll
    for (int rt = 0; rt < 8; ++rt) {
        int4 ss = *(const int4*)&s_src[rt * 16 + quad * 4];
        int4 dd = *(const int4*)&s_dst[rt * 16 + quad * 4];
        unsigned p0 = *(const unsigned*)((const char*)Pu + ((unsigned)ss.x * 256u + jb));
        unsigned q0 = *(const unsigned*)((const char*)Qu + ((unsigned)dd.x * 256u + jb));
        unsigned p1 = *(const unsigned*)((const char*)Pu + ((unsigned)ss.y * 256u + jb));
        unsigned q1 = *(const unsigned*)((const char*)Qu + ((unsigned)dd.y * 256u + jb));
        unsigned p2 = *(const unsigned*)((const char*)Pu + ((unsigned)ss.z * 256u + jb));
        unsigned q2 = *(const unsigned*)((const char*)Qu + ((unsigned)dd.z * 256u + jb));
        unsigned p3 = *(const unsigned*)((const char*)Pu + ((unsigned)ss.w * 256u + jb));
        unsigned q3 = *(const unsigned*)((const char*)Qu + ((unsigned)dd.w * 256u + jb));
        acc[rt][0][0] = bflo(p0) + bflo(q0);
        acc[rt][1][0] = bfhi(p0) + bfhi(q0);
        acc[rt][0][1] = bflo(p1) + bflo(q1);
        acc[rt][1][1] = bfhi(p1) + bfhi(q1);
        acc[rt][0][2] = bflo(p2) + bflo(q2);
        acc[rt][1][2] = bfhi(p2) + bfhi(q2);
        acc[rt][0][3] = bflo(p3) + bflo(q3);
        acc[rt][1][3] = bfhi(p3) + bfhi(q3);
    }
    __syncthreads();   // (B) ea chunk staged

    // layer-1 remainder: single K=32 MFMA chunk (We1 rows 256..287 = chunk 8)
    {
        bf16x8 b0 = *(const bf16x8*)&pWe1[((size_t)(8 * 8 + ct0) * 64 + lane) * 8];
        bf16x8 b1 = *(const bf16x8*)&pWe1[((size_t)(8 * 8 + ct1) * 64 + lane) * 8];
        __builtin_amdgcn_s_setprio(1);
#pragma unroll
        for (int rt = 0; rt < 8; ++rt) {
            bf16x8 a = *(const bf16x8*)&sT[(rt * 16 + lc) * 32 + quad * 8];
            acc[rt][0] = __builtin_amdgcn_mfma_f32_16x16x32_bf16(a, b0, acc[rt][0], 0, 0, 0);
            acc[rt][1] = __builtin_amdgcn_mfma_f32_16x16x32_bf16(a, b1, acc[rt][1], 0, 0, 0);
        }
        __builtin_amdgcn_s_setprio(0);
    }
    __syncthreads();

    // epilogue 1: silu -> sT (bf16, permuted-paired, swizzled)
#pragma unroll
    for (int rt = 0; rt < 8; ++rt)
#pragma unroll
        for (int r = 0; r < 4; ++r) {
            int row = rt * 16 + quad * 4 + r;
            unsigned pk = cvt_pk_bf16(silu_f(acc[rt][0][r]), silu_f(acc[rt][1][r]));
            *(unsigned*)&sT[row * 128 + (jblk ^ ((row >> 1) & 7)) * 8 + joff] = pk;
        }
    __syncthreads();

    // ---- phi_e layer 2: m = t1 @ We2 + be2 (We2 K-rows permuted in pack) ----
#pragma unroll
    for (int rt = 0; rt < 8; ++rt)
#pragma unroll
        for (int ct = 0; ct < 2; ++ct)
#pragma unroll
            for (int r = 0; r < 4; ++r) acc[rt][ct][r] = 0.0f;

    for (int kc = 0; kc < 4; ++kc) {
        bf16x8 b0 = *(const bf16x8*)&pWe2[((size_t)(kc * 8 + ct0) * 64 + lane) * 8];
        bf16x8 b1 = *(const bf16x8*)&pWe2[((size_t)(kc * 8 + ct1) * 64 + lane) * 8];
        __builtin_amdgcn_s_setprio(1);
#pragma unroll
        for (int rt = 0; rt < 8; ++rt) {
            int kb = (kc * 4 + quad) ^ ((lc >> 1) & 7);
            bf16x8 a = *(const bf16x8*)&sT[(rt * 16 + lc) * 128 + kb * 8];
            acc[rt][0] = __builtin_amdgcn_mfma_f32_16x16x32_bf16(a, b0, acc[rt][0], 0, 0, 0);
            acc[rt][1] = __builtin_amdgcn_mfma_f32_16x16x32_bf16(a, b1, acc[rt][1], 0, 0, 0);
        }
        __builtin_amdgcn_s_setprio(0);
    }
    __syncthreads();

    // write m -> sT (bias folded; permuted-paired)
    {
        float bb0 = be2[c0], bb1 = be2[c1];
#pragma unroll
        for (int rt = 0; rt < 8; ++rt)
#pragma unroll
            for (int r = 0; r < 4; ++r) {
                int row = rt * 16 + quad * 4 + r;
                unsigned pk = cvt_pk_bf16(acc[rt][0][r] + bb0, acc[rt][1][r] + bb1);
                *(unsigned*)&sT[row * 128 + (jblk ^ ((row >> 1) & 7)) * 8 + joff] = pk;
            }
    }
    __syncthreads();

    // ---- phi_x (Wx1 K-rows permuted in pack) ----
#pragma unroll
    for (int rt = 0; rt < 8; ++rt)
#pragma unroll
        for (int ct = 0; ct < 2; ++ct)
#pragma unroll
            for (int r = 0; r < 4; ++r) acc[rt][ct][r] = 0.0f;

    for (int kc = 0; kc < 4; ++kc) {
        bf16x8 b0 = *(const bf16x8*)&pWx1[((size_t)(kc * 8 + ct0) * 64 + lane) * 8];
        bf16x8 b1 = *(const bf16x8*)&pWx1[((size_t)(kc * 8 + ct1) * 64 + lane) * 8];
        __builtin_amdgcn_s_setprio(1);
#pragma unroll
        for (int rt = 0; rt < 8; ++rt) {
            int kb = (kc * 4 + quad) ^ ((lc >> 1) & 7);
            bf16x8 a = *(const bf16x8*)&sT[(rt * 16 + lc) * 128 + kb * 8];
            acc[rt][0] = __builtin_amdgcn_mfma_f32_16x16x32_bf16(a, b0, acc[rt][0], 0, 0, 0);
            acc[rt][1] = __builtin_amdgcn_mfma_f32_16x16x32_bf16(a, b1, acc[rt][1], 0, 0, 0);
        }
        __builtin_amdgcn_s_setprio(0);
    }

    // segmented agg scatter: paired column-walk (2 cols per thread, 32 rows)
    {
        const int sp = tid & 63;          // storage pair id
        const int rq = tid >> 6;          // row quarter
        const int cLo = ((sp >> 4) << 5) + (sp & 15);
        const int cHi = cLo + 16;
        const int pblk = sp >> 2;
        const int poff = (sp & 3) * 2;
        const int rb = rq * 32;
        float run0 = 0.0f, run1 = 0.0f;
        int cur = s_dst[rb];
#pragma unroll 8
        for (int r = rb; r < rb + 32; ++r) {
            int d = s_dst[r];
            if (d != cur) {
                atomicAdd(&agg[(size_t)cur * HDIM + cLo], run0);
                atomicAdd(&agg[(size_t)cur * HDIM + cHi], run1);
                run0 = 0.0f; run1 = 0.0f; cur = d;
            }
            unsigned v = *(const unsigned*)&sT[r * 128 + (pblk ^ ((r >> 1) & 7)) * 8 + poff];
            run0 += bflo(v); run1 += bfhi(v);
        }
        atomicAdd(&agg[(size_t)cur * HDIM + cLo], run0);
        atomicAdd(&agg[(size_t)cur * HDIM + cHi], run1);
    }

    // gate epilogue
    {
        float wx0 = Wx2[c0], wx1 = Wx2[c1];
        float bb0 = bx1[c0], bb1 = bx1[c1];
        float gp[8][4];
#pragma unroll
        for (int rt = 0; rt < 8; ++rt)
#pragma unroll
            for (int r = 0; r < 4; ++r)
                gp[rt][r] = silu_f(acc[rt][0][r] + bb0) * wx0 +
                            silu_f(acc[rt][1][r] + bb1) * wx1;
#pragma unroll
        for (int m = 1; m < 16; m <<= 1)
#pragma unroll
            for (int rt = 0; rt < 8; ++rt)
#pragma unroll
                for (int r = 0; r < 4; ++r)
                    gp[rt][r] += __shfl_xor(gp[rt][r], m, 64);
        if (lc == 0) {
#pragma unroll
            for (int rt = 0; rt < 8; ++rt)
#pragma unroll
                for (int r = 0; r < 4; ++r)
                    atomicAdd(&sGate[rt * 16 + quad * 4 + r], gp[rt][r]);
        }
    }
    __syncthreads();

    // segmented dx scatter
    if (tid < 48) {
        const int comp = tid % 3;
        const int ch = tid / 3;
        const float b2 = bx2[0];
        int r = ch * 8;
        float run = 0.0f;
        int cur = s_dst[r];
        for (int k = 0; k < 8; ++k, ++r) {
            int d = s_dst[r];
            if (d != cur) {
                atomicAdd(&dxb[(size_t)cur * 3 + comp], run);
                run = 0.0f; cur = d;
            }
            run += s_dir[r * 3 + comp] * (sGate[r] + b2);
        }
        atomicAdd(&dxb[(size_t)cur * 3 + comp], run);
    }
}

// ==================== FALLBACK edge kernel (128-tile, unchanged) ====================
__global__ __launch_bounds__(256, 4)
void egnn_edge_v4(const short* __restrict__ h_bf, const float* __restrict__ x,
                  const int* __restrict__ ei, const float* __restrict__ ea,
                  const int* __restrict__ eid_sorted,
                  const short* __restrict__ pWe1, const short* __restrict__ pWe2,
                  const short* __restrict__ pWx1,
                  const float* __restrict__ be1, const float* __restrict__ be2,
                  const float* __restrict__ bx1, const float* __restrict__ Wx2,
                  const float* __restrict__ bx2,
                  float* __restrict__ agg, float* __restrict__ dxb) {
    __shared__ __align__(16) short sT[128 * 128];
    __shared__ int s_dst[128], s_eid[128];
    __shared__ float s_dist[128], s_dir[384], sGate[128];

    const int tid = threadIdx.x;
    const int lane = tid & 63;
    const int w = tid >> 6;
    const int lc = lane & 15;
    const int quad = lane >> 4;

    int bix = blockIdx.x;
    int bid = (bix < 6248) ? (bix & 7) * 781 + (bix >> 3) : bix;
    const int e0 = bid * 128;

    const int part = lane & 3;
    const int r0 = w * 32 + (lane >> 2);
    const int r1 = r0 + 16;
    const int eS0 = eid_sorted[e0 + r0], eS1 = eid_sorted[e0 + r1];
    const int es0 = ei[eS0], ed0 = ei[N_EDGES + eS0];
    const int es1 = ei[eS1], ed1 = ei[N_EDGES + eS1];

#define STAGE_H(kc_, buf_) do {                                              \
        const int ss = ((kc_) < 4);                                          \
        const int ko = ((kc_) & 3) * 32 + part * 8;                          \
        gl_lds16(h_bf + (size_t)(ss ? es0 : ed0) * 128 + ko,                 \
                 &sT[(buf_) * 4096 + w * 1024]);                             \
        gl_lds16(h_bf + (size_t)(ss ? es1 : ed1) * 128 + ko,                 \
                 &sT[(buf_) * 4096 + w * 1024 + 512]);                       \
    } while (0)

    STAGE_H(0, 0);

    if (tid < 128) {
        int e = eid_sorted[e0 + tid];
        s_eid[tid] = e;
        int s = ei[e], d = ei[N_EDGES + e];
        s_dst[tid] = d;
        float ddx = x[d * 3 + 0] - x[s * 3 + 0];
        float ddy = x[d * 3 + 1] - x[s * 3 + 1];
        float ddz = x[d * 3 + 2] - x[s * 3 + 2];
        float dot = ddx * ddx + ddy * ddy + ddz * ddz;
        s_dist[tid] = sqrtf(dot + 1e-9f);
        float inv = fast_rcp(sqrtf(dot) + 1e-9f);
        s_dir[tid * 3 + 0] = ddx * inv;
        s_dir[tid * 3 + 1] = ddy * inv;
        s_dir[tid * 3 + 2] = ddz * inv;
        sGate[tid] = 0.0f;
    }

    const int ct0 = 2 * w, ct1 = 2 * w + 1;
    const int c0 = ct0 * 16 + lc, c1 = c0 + 16;
    const int jblk = w * 4 + (lc >> 2);
    const int joff = (lc & 3) * 2;

    floatx4 acc[8][2];
#pragma unroll
    for (int rt = 0; rt < 8; ++rt)
#pragma unroll
        for (int ct = 0; ct < 2; ++ct)
#pragma unroll
            for (int r = 0; r < 4; ++r) acc[rt][ct][r] = 0.0f;

    for (int kc = 0; kc < 9; ++kc) {
        __syncthreads();
        if (kc < 7) {
            STAGE_H(kc + 1, (kc + 1) & 1);
        } else if (kc == 7) {
            if (tid < 128) {
                const float4* p = (const float4*)&ea[(size_t)s_eid[tid] * 16];
                float4 a = p[0], b = p[1], c = p[2], d = p[3];
                uint4* dst = (uint4*)&sT[0 * 4096 + tid * 32];
                dst[0] = make_uint4(cvt_pk_bf16(a.x, a.y), cvt_pk_bf16(a.z, a.w),
                                    cvt_pk_bf16(b.x, b.y), cvt_pk_bf16(b.z, b.w));
                dst[1] = make_uint4(cvt_pk_bf16(c.x, c.y), cvt_pk_bf16(c.z, c.w),
                                    cvt_pk_bf16(d.x, d.y), cvt_pk_bf16(d.z, d.w));
                dst[2] = make_uint4(cvt_pk_bf16(s_dist[tid], 0.0f), 0u, 0u, 0u);
                dst[3] = make_uint4(0u, 0u, 0u, 0u);
            }
        }
        const int buf = kc & 1;
        bf16x8 b0 = *(const bf16x8*)&pWe1[((size_t)(kc * 8 + ct0) * 64 + lane) * 8];
        bf16x8 b1 = *(const bf16x8*)&pWe1[((size_t)(kc * 8 + ct1) * 64 + lane) * 8];
#pragma unroll
        for (int rt = 0; rt < 8; ++rt) {
            bf16x8 a = *(const bf16x8*)&sT[buf * 4096 + (rt * 16 + lc) * 32 + quad * 8];
            acc[rt][0] = __builtin_amdgcn_mfma_f32_16x16x32_bf16(a, b0, acc[rt][0], 0, 0, 0);
            acc[rt][1] = __builtin_amdgcn_mfma_f32_16x16x32_bf16(a, b1, acc[rt][1], 0, 0, 0);
        }
    }
    __syncthreads();

    {
        float bb0 = be1[c0], bb1 = be1[c1];
#pragma unroll
        for (int rt = 0; rt < 8; ++rt)
#pragma unroll
            for (int r = 0; r < 4; ++r) {
                int row = rt * 16 + quad * 4 + r;
                unsigned pk = cvt_pk_bf16(silu_f(acc[rt][0][r] + bb0),
                                          silu_f(acc[rt][1][r] + bb1));
                *(unsigned*)&sT[row * 128 + (jblk ^ ((row >> 1) & 7)) * 8 + joff] = pk;
            }
    }
    __syncthreads();

#pragma unroll
    for (int rt = 0; rt < 8; ++rt)
#pragma unroll
        for (int ct = 0; ct < 2; ++ct)
#pragma unroll
            for (int r = 0; r < 4; ++r) acc[rt][ct][r] = 0.0f;

    for (int kc = 0; kc < 4; ++kc) {
        bf16x8 b0 = *(const bf16x8*)&pWe2[((size_t)(kc * 8 + ct0) * 64 + lane) * 8];
        bf16x8 b1 = *(const bf16x8*)&pWe2[((size_t)(kc * 8 + ct1) * 64 + lane) * 8];
#pragma unroll
        for (int rt = 0; rt < 8; ++rt) {
            int kb = (kc * 4 + quad) ^ ((lc >> 1) & 7);
            bf16x8 a = *(const bf16x8*)&sT[(rt * 16 + lc) * 128 + kb * 8];
            acc[rt][0] = __builtin_amdgcn_mfma_f32_16x16x32_bf16(a, b0, acc[rt][0], 0, 0, 0);
            acc[rt][1] = __builtin_amdgcn_mfma_f32_16x16x32_bf16(a, b1, acc[rt][1], 0, 0, 0);
        }
    }
    __syncthreads();

    {
        float bb0 = be2[c0], bb1 = be2[c1];
#pragma unroll
        for (int rt = 0; rt < 8; ++rt)
#pragma unroll
            for (int r = 0; r < 4; ++r) {
                int row = rt * 16 + quad * 4 + r;
                unsigned pk = cvt_pk_bf16(acc[rt][0][r] + bb0, acc[rt][1][r] + bb1);
                *(unsigned*)&sT[row * 128 + (jblk ^ ((row >> 1) & 7)) * 8 + joff] = pk;
            }
    }
    __syncthreads();

#pragma unroll
    for (int rt = 0; rt < 8; ++rt)
#pragma unroll
        for (int ct = 0; ct < 2; ++ct)
#pragma unroll
            for (int r = 0; r < 4; ++r) acc[rt][ct][r] = 0.0f;

    for (int kc = 0; kc < 4; ++kc) {
        bf16x8 b0 = *(const bf16x8*)&pWx1[((size_t)(kc * 8 + ct0) * 64 + lane) * 8];
        bf16x8 b1 = *(const bf16x8*)&pWx1[((size_t)(kc * 8 + ct1) * 64 + lane) * 8];
#pragma unroll
        for (int rt = 0; rt < 8; ++rt) {
            int kb = (kc * 4 + quad) ^ ((lc >> 1) & 7);
            bf16x8 a = *(const bf16x8*)&sT[(rt * 16 + lc) * 128 + kb * 8];
            acc[rt][0] = __builtin_amdgcn_mfma_f32_16x16x32_bf16(a, b0, acc[rt][0], 0, 0, 0);
            acc[rt][1] = __builtin_amdgcn_mfma_f32_16x16x32_bf16(a, b1, acc[rt][1], 0, 0, 0);
        }
    }

    {
        const int sp = tid & 63;
        const int rq = tid >> 6;
        const int cLo = ((sp >> 4) << 5) + (sp & 15);
        const int cHi = cLo + 16;
        const int pblk = sp >> 2;
        const int poff = (sp & 3) * 2;
        const int rb = rq * 32;
        float run0 = 0.0f, run1 = 0.0f;
        int cur = s_dst[rb];
#pragma unroll 8
        for (int r = rb; r < rb + 32; ++r) {
            int d = s_dst[r];
            if (d != cur) {
                atomicAdd(&agg[(size_t)cur * HDIM + cLo], run0);
                atomicAdd(&agg[(size_t)cur * HDIM + cHi], run1);
                run0 = 0.0f; run1 = 0.0f; cur = d;
            }
            unsigned v = *(const unsigned*)&sT[r * 128 + (pblk ^ ((r >> 1) & 7)) * 8 + poff];
            run0 += bflo(v); run1 += bfhi(v);
        }
        atomicAdd(&agg[(size_t)cur * HDIM + cLo], run0);
        atomicAdd(&agg[(size_t)cur * HDIM + cHi], run1);
    }

    {
        float wx0 = Wx2[c0], wx1 = Wx2[c1];
        float bb0 = bx1[c0], bb1 = bx1[c1];
        float gp[8][4];
#pragma unroll
        for (int rt = 0; rt < 8; ++rt)
#pragma unroll
            for (int r = 0; r < 4; ++r)
                gp[rt][r] = silu_f(acc[rt][0][r] + bb0) * wx0 +
                            silu_f(acc[rt][1][r] + bb1) * wx1;
#pragma unroll
        for (int m = 1; m < 16; m <<= 1)
#pragma unroll
            for (int rt = 0; rt < 8; ++rt)
#pragma unroll
                for (int r = 0; r < 4; ++r)
                    gp[rt][r] += __shfl_xor(gp[rt][r], m, 64);
        if (lc == 0) {
#pragma unroll
            for (int rt = 0; rt < 8; ++rt)
#pragma unroll
                for (int r = 0; r < 4; ++r)
                    atomicAdd(&sGate[rt * 16 + quad * 4 + r], gp[rt][r]);
        }
    }
    __syncthreads();

    if (tid < 48) {
        const int comp = tid % 3;
        const int ch = tid / 3;
        const float b2 = bx2[0];
        int r = ch * 8;
        float run = 0.0f;
        int cur = s_dst[r];
        for (int k = 0; k < 8; ++k, ++r) {
            int d = s_dst[r];
            if (d != cur) {
                atomicAdd(&dxb[(size_t)cur * 3 + comp], run);
                run = 0.0f; cur = d;
            }
            run += s_dir[r * 3 + comp] * (sGate[r] + b2);
        }
        atomicAdd(&dxb[(size_t)cur * 3 + comp], run);
    }
#undef STAGE_H
}

__global__ __launch_bounds__(256, 4)
void egnn_node_mfma(const short* __restrict__ h_bf, const float* __restrict__ h,
                    const float* __restrict__ x,
                    const float* __restrict__ agg, const float* __restrict__ dxb,
                    const short* __restrict__ pWh1, const short* __restrict__ pWh2,
                    const float* __restrict__ bh1, const float* __restrict__ bh2,
                    const float* __restrict__ ln_g, const float* __restrict__ ln_b,
                    float* __restrict__ hout, float* __restrict__ xout) {
    __shared__ __align__(16) short sT[64 * 128];
    __shared__ float sS1[64], sS2[64];

    const int tid = threadIdx.x;
    const int lane = tid & 63;
    const int w = tid >> 6;
    const int lc = lane & 15;
    const int quad = lane >> 4;
    const int n0 = blockIdx.x * 64;

#define STAGE_N(kc_, buf_) do {                                              \
        if ((kc_) < 4) {                                                     \
            const int ko = (kc_) * 32 + (lane & 3) * 8;                      \
            const int row = w * 16 + (lane >> 2);                            \
            const int n = (n0 + row < N_NODES) ? n0 + row : N_NODES - 1;     \
            gl_lds16(h_bf + (size_t)n * 128 + ko,                            \
                     &sT[(buf_) * 2048 + w * 512]);                          \
        } else {                                                             \
            const int srow = tid >> 2, prt = tid & 3;                        \
            const int n = (n0 + srow < N_NODES) ? n0 + srow : N_NODES - 1;   \
            const float4* p = (const float4*)&agg[(size_t)n * HDIM +         \
                                                  ((kc_) & 3) * 32 + prt * 8]; \
            float4 a = p[0], b = p[1];                                       \
            *(uint4*)&sT[(buf_) * 2048 + srow * 32 + prt * 8] =              \
                make_uint4(cvt_pk_bf16(a.x, a.y), cvt_pk_bf16(a.z, a.w),     \
                           cvt_pk_bf16(b.x, b.y), cvt_pk_bf16(b.z, b.w));    \
        }                                                                    \
    } while (0)

    STAGE_N(0, 0);
    if (tid < 64) { sS1[tid] = 0.0f; sS2[tid] = 0.0f; }

    const int ct0 = 2 * w, ct1 = 2 * w + 1;
    const int c0 = ct0 * 16 + lc, c1 = c0 + 16;
    const int jblk = w * 4 + (lc >> 2);
    const int joff = (lc & 3) * 2;

    floatx4 acc[4][2];
#pragma unroll
    for (int rt = 0; rt < 4; ++rt)
#pragma unroll
        for (int ct = 0; ct < 2; ++ct)
#pragma unroll
            for (int r = 0; r < 4; ++r) acc[rt][ct][r] = 0.0f;

    for (int kc = 0; kc < 8; ++kc) {
        __syncthreads();
        if (kc < 7) STAGE_N(kc + 1, (kc + 1) & 1);
        const int buf = kc & 1;
        bf16x8 b0 = *(const bf16x8*)&pWh1[((size_t)(kc * 8 + ct0) * 64 + lane) * 8];
        bf16x8 b1 = *(const bf16x8*)&pWh1[((size_t)(kc * 8 + ct1) * 64 + lane) * 8];
        __builtin_amdgcn_s_setprio(1);
#pragma unroll
        for (int rt = 0; rt < 4; ++rt) {
            bf16x8 a = *(const bf16x8*)&sT[buf * 2048 + (rt * 16 + lc) * 32 + quad * 8];
            acc[rt][0] = __builtin_amdgcn_mfma_f32_16x16x32_bf16(a, b0, acc[rt][0], 0, 0, 0);
            acc[rt][1] = __builtin_amdgcn_mfma_f32_16x16x32_bf16(a, b1, acc[rt][1], 0, 0, 0);
        }
        __builtin_amdgcn_s_setprio(0);
    }
    __syncthreads();

    {
        float bb0 = bh1[c0], bb1 = bh1[c1];
#pragma unroll
        for (int rt = 0; rt < 4; ++rt)
#pragma unroll
            for (int r = 0; r < 4; ++r) {
                int row = rt * 16 + quad * 4 + r;
                unsigned pk = cvt_pk_bf16(silu_f(acc[rt][0][r] + bb0),
                                          silu_f(acc[rt][1][r] + bb1));
                *(unsigned*)&sT[row * 128 + (jblk ^ ((row >> 1) & 7)) * 8 + joff] = pk;
            }
    }
    __syncthreads();

#pragma unroll
    for (int rt = 0; rt < 4; ++rt)
#pragma unroll
        for (int ct = 0; ct < 2; ++ct)
#pragma unroll
            for (int r = 0; r < 4; ++r) acc[rt][ct][r] = 0.0f;

    for (int kc = 0; kc < 4; ++kc) {
        bf16x8 b0 = *(const bf16x8*)&pWh2[((size_t)(kc * 8 + ct0) * 64 + lane) * 8];
        bf16x8 b1 = *(const bf16x8*)&pWh2[((size_t)(kc * 8 + ct1) * 64 + lane) * 8];
        __builtin_amdgcn_s_setprio(1);
#pragma unroll
        for (int rt = 0; rt < 4; ++rt) {
            int kb = (kc * 4 + quad) ^ ((lc >> 1) & 7);
            bf16x8 a = *(const bf16x8*)&sT[(rt * 16 + lc) * 128 + kb * 8];
            acc[rt][0] = __builtin_amdgcn_mfma_f32_16x16x32_bf16(a, b0, acc[rt][0], 0, 0, 0);
            acc[rt][1] = __builtin_amdgcn_mfma_f32_16x16x32_bf16(a, b1, acc[rt][1], 0, 0, 0);
        }
        __builtin_amdgcn_s_setprio(0);
    }

    {
        float bb0 = bh2[c0], bb1 = bh2[c1];
#pragma unroll
        for (int rt = 0; rt < 4; ++rt)
#pragma unroll
            for (int r = 0; r < 4; ++r) {
                int row = rt * 16 + quad * 4 + r;
                int n = n0 + row;
                int nc = (n < N_NODES) ? n : (N_NODES - 1);
                float v0 = acc[rt][0][r] + bb0 + h[(size_t)nc * HDIM + c0];
                float v1 = acc[rt][1][r] + bb1 + h[(size_t)nc * HDIM + c1];
                acc[rt][0][r] = v0;
                acc[rt][1][r] = v1;
                float s1 = v0 + v1;
                float s2 = v0 * v0 + v1 * v1;
#pragma unroll
                for (int m = 1; m < 16; m <<= 1) {
                    s1 += __shfl_xor(s1, m, 64);
                    s2 += __shfl_xor(s2, m, 64);
                }
                if (lc == 0) {
                    atomicAdd(&sS1[row], s1);
                    atomicAdd(&sS2[row], s2);
                }
            }
    }
    __syncthreads();
    {
        float g0 = ln_g[c0], g1 = ln_g[c1];
        float lb0 = ln_b[c0], lb1 = ln_b[c1];
#pragma unroll
        for (int rt = 0; rt < 4; ++rt)
#pragma unroll
            for (int r = 0; r < 4; ++r) {
                int row = rt * 16 + quad * 4 + r;
                int n = n0 + row;
                if (n < N_NODES) {
                    float mu = sS1[row] * (1.0f / 128.0f);
                    float var = sS2[row] * (1.0f / 128.0f) - mu * mu;
                    float rs = rsqrtf(var + 1e-5f);
                    hout[(size_t)n * HDIM + c0] = (acc[rt][0][r] - mu) * rs * g0 + lb0;
                    hout[(size_t)n * HDIM + c1] = (acc[rt][1][r] - mu) * rs * g1 + lb1;
                }
            }
    }

    if (tid < 192) {
        int n = n0 + tid / 3;
        int d = tid - (tid / 3) * 3;
        if (n < N_NODES) xout[(size_t)n * 3 + d] = x[(size_t)n * 3 + d] + dxb[(size_t)n * 3 + d];
    }
#undef STAGE_N
}

extern "C" void kernel_launch(void* const* d_in, const int* in_sizes, int n_in,
                              void* d_out, int out_size, void* d_ws, size_t ws_size,
                              hipStream_t stream) {
    (void)in_sizes; (void)n_in; (void)out_size;

    const float* h   = (const float*)d_in[0];
    const float* x   = (const float*)d_in[1];
    const int*   ei  = (const int*)d_in[2];
    const float* ea  = (const float*)d_in[3];
    const float* We1 = (const float*)d_in[4];
    const float* be1 = (const float*)d_in[5];
    const float* We2 = (const float*)d_in[6];
    const float* be2 = (const float*)d_in[7];
    const float* Wh1 = (const float*)d_in[8];
    const float* bh1 = (const float*)d_in[9];
    const float* Wh2 = (const float*)d_in[10];
    const float* bh2 = (const float*)d_in[11];
    const float* Wx1 = (const float*)d_in[12];
    const float* bx1 = (const float*)d_in[13];
    const float* Wx2 = (const float*)d_in[14];
    const float* bx2 = (const float*)d_in[15];
    const float* lng = (const float*)d_in[16];
    const float* lnb = (const float*)d_in[17];

    float* hout = (float*)d_out;
    float* xout = hout + (size_t)N_NODES * HDIM;

    const size_t CH = 8 * 64 * 8;
    const size_t oWe1 = 0, oWh1 = 17 * CH, oWh2 = 25 * CH;
    const size_t oWe2 = 9 * CH, oWx1 = 13 * CH;
    const size_t pwElems = 29 * CH;

    const size_t aggElems = (size_t)N_NODES * HDIM;
    const size_t dxbElems = (size_t)N_NODES * 3;
    const size_t aggB = aggElems * 4, dxbB = dxbElems * 4;
    const size_t pwB = pwElems * 2;
    const size_t hbB = (size_t)N_NODES * HDIM * 2;
    const size_t cntB = (size_t)N_NODES * 4;
    const size_t eidB = (size_t)N_EDGES * 4;

    char* ws = (char*)d_ws;
    // bigws needs 4-shadow cnt + 4-shadow cursor (8 * cntB)
    const bool bigws = ws_size >= aggB + dxbB + pwB + hbB + 8 * cntB + eidB;

    float* agg; float* dxb; short* pw; short* h_bf; int* cnt; int* cursor; int* eid;
    if (bigws) {
        agg    = (float*)ws;
        dxb    = (float*)(ws + aggB);
        pw     = (short*)(ws + aggB + dxbB);
        h_bf   = (short*)(ws + aggB + dxbB + pwB);
        cnt    = (int*)(ws + aggB + dxbB + pwB + hbB);                 // cnt4[4][N]
        cursor = (int*)(ws + aggB + dxbB + pwB + hbB + 4 * cntB);      // cursor4[4][N]
        eid    = (int*)(ws + aggB + dxbB + pwB + hbB + 8 * cntB);
    } else {
        pw     = (short*)ws;
        h_bf   = (short*)(ws + pwB);
        cnt    = (int*)(ws + pwB + hbB);
        cursor = (int*)(ws + pwB + hbB + cntB);
        eid    = (int*)(ws + pwB + hbB + 2 * cntB);
        agg    = (float*)d_out;    // aliasing safe: node blocks read their agg/
        dxb    = agg + aggElems;   // dxb rows before writing hout/xout rows
    }

    if (bigws) {
        // P/Q live in d_out (free scratch until node kernel writes hout/xout)
        unsigned* Pu = (unsigned*)d_out;
        unsigned* Qu = Pu + (size_t)N_NODES * 64;

        hipMemsetAsync(cnt, 0, 4 * cntB, stream);
        // K1: hist (4-shadow) | pack h | pack weights | zero agg+dxb
        fused_prep1<<<7908, 256, 0, stream>>>(h, h_bf, We1, We2, Wx1, Wh1, Wh2,
                                              pw, ei, cnt, (float4*)agg);
        // K2: scan (block 0) || P/Q precompute (blocks 1..782)
        scan_pq_kernel<<<1 + (N_NODES + 63) / 64, 256, 0, stream>>>(
            cnt, cursor, h_bf, pw + oWe1, be1, Pu, Qu);
        // K3: scatter (4-shadow)
        scatter4_kernel<<<N_EDGES / 256, 256, 0, stream>>>(ei, cursor, eid);
        // K4: edge (128-tile)
        egnn_edge_pq<<<N_EDGES / 128, 256, 0, stream>>>(
            Pu, Qu, x, ei, ea, eid, pw + oWe1, pw + oWe2, pw + oWx1,
            be2, bx1, Wx2, bx2, agg, dxb);
    } else {
        hipMemsetAsync(agg, 0, aggB, stream);
        hipMemsetAsync(dxb, 0, dxbB, stream);
        hipMemsetAsync(cnt, 0, cntB, stream);
        pack_bf16_kernel<<<(N_NODES * HDIM / 8 + 255) / 256, 256, 0, stream>>>(
            h, h_bf, N_NODES * HDIM / 8);
        pack_all_w<<<(29 * 512 + 255) / 256, 256, 0, stream>>>(We1, We2, Wx1, Wh1, Wh2, pw);
        hist_kernel<<<(N_EDGES + 255) / 256, 256, 0, stream>>>(ei, cnt);
        scan_kernel<<<1, 1024, 0, stream>>>(cnt, cursor, N_NODES / 4);
        scatter_kernel<<<(N_EDGES + 255) / 256, 256, 0, stream>>>(ei, cursor, eid);
        egnn_edge_v4<<<N_EDGES / 128, 256, 0, stream>>>(
            h_bf, x, ei, ea, eid, pw + oWe1, pw + oWe2, pw + oWx1,
            be1, be2, bx1, Wx2, bx2, agg, dxb);
    }

    // K5: node
    egnn_node_mfma<<<(N_NODES + 63) / 64, 256, 0, stream>>>(
        h_bf, h, x, agg, dxb, pw + oWh1, pw + oWh2,
        bh1, bh2, lng, lnb, hout, xout);
}

// Round 6
// 437.458 us; speedup vs baseline: 1.2025x; 1.1812x over previous
//
#include <hip/hip_runtime.h>
#include <math.h>

#define N_NODES 50000
#define N_EDGES 800000
#define HDIM 128
// zero region: agg (N x 128 f32) + dxb (N x 3 f32) = 1,637,500 float4
#define ZERO_F4 1637500

typedef __attribute__((ext_vector_type(8))) short bf16x8;
typedef __attribute__((ext_vector_type(4))) float floatx4;

__device__ __forceinline__ unsigned f2bf_u(float f) {
    union { float f; unsigned u; } x; x.f = f;
    return (x.u + 0x7FFFu + ((x.u >> 16) & 1u)) >> 16;
}
__device__ __forceinline__ short f2bf(float f) { return (short)f2bf_u(f); }
__device__ __forceinline__ float bf2f(short s) {
    union { float f; unsigned u; } x; x.u = ((unsigned)(unsigned short)s) << 16;
    return x.f;
}
// packed bf16 pair: lo = bf16(a), hi = bf16(b)  (HW RNE, 1 instr)
__device__ __forceinline__ unsigned cvt_pk_bf16(float a, float b) {
    unsigned r;
    asm("v_cvt_pk_bf16_f32 %0, %1, %2" : "=v"(r) : "v"(a), "v"(b));
    return r;
}
__device__ __forceinline__ float bflo(unsigned u) {
    union { float f; unsigned u; } x; x.u = u << 16; return x.f;
}
__device__ __forceinline__ float bfhi(unsigned u) {
    union { float f; unsigned u; } x; x.u = u & 0xffff0000u; return x.f;
}
__device__ __forceinline__ float fast_rcp(float x) {
    float r; asm("v_rcp_f32 %0, %1" : "=v"(r) : "v"(x)); return r;
}
__device__ __forceinline__ float silu_f(float v) {
    return v * fast_rcp(1.0f + __expf(-v));
}

// async 16B/lane global->LDS DMA; lds base wave-uniform, HW adds lane*16.
__device__ __forceinline__ void gl_lds16(const void* g, void* l) {
    __builtin_amdgcn_global_load_lds(
        (const __attribute__((address_space(1))) unsigned int*)g,
        (__attribute__((address_space(3))) unsigned int*)l, 16, 0, 0);
}

// Storage-column permutation: storage j holds original activation column
// p(j) = (j&~31) + ((j&31)>>1) + (j&1)*16, so a lane's (c0, c0+16) acc pair
// lands in ADJACENT shorts -> one ds_write_b32 / ds_read_b32 per pair.
// Weights consuming these activations (We2, Wx1, Wh2) have K rows permuted
// by p() in the pack; MFMA contraction is K-order-invariant.
__device__ __forceinline__ int permk(int k) {
    return (k & ~31) + ((k & 31) >> 1) + (k & 1) * 16;
}

// ---- shared bodies ----
__device__ __forceinline__ void pack_w_body(int t, const float* We1, const float* We2,
                                            const float* Wx1, const float* Wh1,
                                            const float* Wh2, short* pw) {
    int u = t >> 9;
    const float* W; int K, base; bool pk;
    if (u < 9)       { W = We1; K = 273; base = 0;  pk = false; }
    else if (u < 13) { W = We2; K = 128; base = 9;  pk = true;  }
    else if (u < 17) { W = Wx1; K = 128; base = 13; pk = true;  }
    else if (u < 25) { W = Wh1; K = 256; base = 17; pk = false; }
    else             { W = Wh2; K = 128; base = 25; pk = true;  }
    int tl = t - base * 512;
    int lane = tl & 63;
    int ctk = tl >> 6;
    int ct = ctk & 7, kc = ctk >> 3;
    int c = ct * 16 + (lane & 15);
    int kb = kc * 32 + (lane >> 4) * 8;
    bf16x8 v;
#pragma unroll
    for (int j = 0; j < 8; ++j) {
        int k = kb + j;
        int ks = pk ? permk(k) : k;
        v[j] = (k < K) ? f2bf(W[(size_t)ks * HDIM + c]) : (short)0;
    }
    *(bf16x8*)&pw[(size_t)t * 8] = v;
}

__device__ __forceinline__ void pack_h_body(int t, const float* src, short* dst) {
    const float4* p = (const float4*)(src + (size_t)t * 8);
    float4 a = p[0], b = p[1];
    uint4 o;
    o.x = cvt_pk_bf16(a.x, a.y);
    o.y = cvt_pk_bf16(a.z, a.w);
    o.z = cvt_pk_bf16(b.x, b.y);
    o.w = cvt_pk_bf16(b.z, b.w);
    *(uint4*)(dst + (size_t)t * 8) = o;
}

// ---- fused prep 1: hist (4-shadow) | pack h | pack weights ----
// Shadow k = e&3 == tid&3 (blocks are 256 = 0 mod 4); same key in scatter.
__global__ __launch_bounds__(256)
void fused_prep1(const float* __restrict__ h, short* __restrict__ h_bf,
                 const float* __restrict__ We1, const float* __restrict__ We2,
                 const float* __restrict__ Wx1, const float* __restrict__ Wh1,
                 const float* __restrict__ Wh2, short* __restrict__ pw,
                 const int* __restrict__ ei, int* __restrict__ cnt4) {
    int bid = blockIdx.x, tid = threadIdx.x;
    if (bid < 3125) {                       // hist: 3125*256 == N_EDGES
        int e = bid * 256 + tid;
        atomicAdd(&cnt4[(tid & 3) * N_NODES + ei[N_EDGES + e]], 1);
    } else if (bid < 6250) {                // pack h: 3125*256 == N*H/8
        pack_h_body((bid - 3125) * 256 + tid, h, h_bf);
    } else {                                // pack weights
        int t = (bid - 6250) * 256 + tid;
        if (t < 29 * 512) pack_w_body(t, We1, We2, Wx1, Wh1, Wh2, pw);
    }
}

// ---- standalone versions (fallback path) ----
__global__ void pack_all_w(const float* __restrict__ We1, const float* __restrict__ We2,
                           const float* __restrict__ Wx1, const float* __restrict__ Wh1,
                           const float* __restrict__ Wh2, short* __restrict__ pw) {
    int t = blockIdx.x * 256 + threadIdx.x;
    if (t < 29 * 512) pack_w_body(t, We1, We2, Wx1, Wh1, Wh2, pw);
}

__global__ void pack_bf16_kernel(const float* __restrict__ src, short* __restrict__ dst,
                                 int n8) {
    int t = blockIdx.x * 256 + threadIdx.x;
    if (t < n8) pack_h_body(t, src, dst);
}

__global__ void hist_kernel(const int* __restrict__ ei, int* __restrict__ cnt) {
    int e = blockIdx.x * 256 + threadIdx.x;
    if (e < N_EDGES) atomicAdd(&cnt[ei[N_EDGES + e]], 1);
}

// int4-per-thread exclusive scan (fallback, n multiple of 4)
__global__ __launch_bounds__(1024)
void scan_kernel(const int* __restrict__ cnt, int* __restrict__ cursor, int n4) {
    __shared__ int wsum[16];
    __shared__ int s_carry;
    const int tid = threadIdx.x;
    const int lane = tid & 63, wid = tid >> 6;
    if (tid == 0) s_carry = 0;
    __syncthreads();
    for (int base = 0; base < n4; base += 1024) {
        int i = base + tid;
        int4 v = make_int4(0, 0, 0, 0);
        if (i < n4) v = ((const int4*)cnt)[i];
        int t0 = v.x, t1 = t0 + v.y, t2 = t1 + v.z, tot = t2 + v.w;
        int s = tot;
#pragma unroll
        for (int off = 1; off < 64; off <<= 1) {
            int sh = __shfl_up(s, off, 64);
            if (lane >= off) s += sh;
        }
        if (lane == 63) wsum[wid] = s;
        __syncthreads();
        if (tid < 16) {
            int t = wsum[tid];
            int sc = t;
#pragma unroll
            for (int off = 1; off < 16; off <<= 1) {
                int tt = __shfl_up(sc, off, 64);
                if (lane >= off) sc += tt;
            }
            wsum[tid] = sc - t;   // exclusive
        }
        __syncthreads();
        int excl = (s - tot) + wsum[wid] + s_carry;
        if (i < n4) {
            int4 o;
            o.x = excl; o.y = excl + t0; o.z = excl + t1; o.w = excl + t2;
            ((int4*)cursor)[i] = o;
        }
        __syncthreads();
        if (tid == 1023) s_carry = excl + tot;
        __syncthreads();
    }
}

// 4-shadow scan: degree(d) = sum_k cnt4[k][d]; cursor4[k][d] = csr_start(d)
// + sum_{j<k} cnt4[j][d]. Layout: shadow slices of 50000 ints (12500 int4).
__global__ __launch_bounds__(1024)
void scan4_kernel(const int* __restrict__ cnt4, int* __restrict__ cursor4, int n4) {
    __shared__ int wsum[16];
    __shared__ int s_carry;
    const int tid = threadIdx.x;
    const int lane = tid & 63, wid = tid >> 6;
    if (tid == 0) s_carry = 0;
    __syncthreads();
    for (int base = 0; base < n4; base += 1024) {
        int i = base + tid;
        int4 a0 = make_int4(0,0,0,0), a1 = a0, a2 = a0, a3 = a0;
        if (i < n4) {
            a0 = ((const int4*)cnt4)[i];
            a1 = ((const int4*)cnt4)[n4 + i];
            a2 = ((const int4*)cnt4)[2 * n4 + i];
            a3 = ((const int4*)cnt4)[3 * n4 + i];
        }
        int4 E;   // per-node total degree
        E.x = a0.x + a1.x + a2.x + a3.x;
        E.y = a0.y + a1.y + a2.y + a3.y;
        E.z = a0.z + a1.z + a2.z + a3.z;
        E.w = a0.w + a1.w + a2.w + a3.w;
        int t0 = E.x, t1 = t0 + E.y, t2 = t1 + E.z, tot = t2 + E.w;
        int s = tot;
#pragma unroll
        for (int off = 1; off < 64; off <<= 1) {
            int sh = __shfl_up(s, off, 64);
            if (lane >= off) s += sh;
        }
        if (lane == 63) wsum[wid] = s;
        __syncthreads();
        if (tid < 16) {
            int t = wsum[tid];
            int sc = t;
#pragma unroll
            for (int off = 1; off < 16; off <<= 1) {
                int tt = __shfl_up(sc, off, 64);
                if (lane >= off) sc += tt;
            }
            wsum[tid] = sc - t;   // exclusive
        }
        __syncthreads();
        int excl = (s - tot) + wsum[wid] + s_carry;
        if (i < n4) {
            int4 ex;
            ex.x = excl;
            ex.y = excl + t0;
            ex.z = excl + t1;
            ex.w = excl + t2;
            int4 c0 = ex;
            int4 c1; c1.x = c0.x + a0.x; c1.y = c0.y + a0.y; c1.z = c0.z + a0.z; c1.w = c0.w + a0.w;
            int4 c2; c2.x = c1.x + a1.x; c2.y = c1.y + a1.y; c2.z = c1.z + a1.z; c2.w = c1.w + a1.w;
            int4 c3; c3.x = c2.x + a2.x; c3.y = c2.y + a2.y; c3.z = c2.z + a2.z; c3.w = c2.w + a2.w;
            ((int4*)cursor4)[i] = c0;
            ((int4*)cursor4)[n4 + i] = c1;
            ((int4*)cursor4)[2 * n4 + i] = c2;
            ((int4*)cursor4)[3 * n4 + i] = c3;
        }
        __syncthreads();
        if (tid == 1023) s_carry = excl + tot;
        __syncthreads();
    }
}

__global__ void scatter_kernel(const int* __restrict__ ei, int* __restrict__ cursor,
                               int* __restrict__ eid) {
    int e = blockIdx.x * 256 + threadIdx.x;
    if (e >= N_EDGES) return;
    int d = ei[N_EDGES + e];
    int pos = atomicAdd(&cursor[d], 1);
    eid[pos] = e;
}

// ---- fused prep 2: scatter (4-shadow) | zero agg+dxb | P/Q precompute ----
__global__ __launch_bounds__(256, 4)
void fused_prep2(const int* __restrict__ ei, int* __restrict__ cursor4,
                 int* __restrict__ eid,
                 const short* __restrict__ h_bf, const short* __restrict__ pWe1,
                 const float* __restrict__ be1,
                 unsigned* __restrict__ Pu, unsigned* __restrict__ Qu,
                 float4* __restrict__ zbase) {
    __shared__ __align__(16) short sA[2 * 2048];
    const int bid = blockIdx.x, tid = threadIdx.x;
    if (bid < 3125) {                        // scatter, shadow k = e&3
        int e = bid * 256 + tid;
        int d = ei[N_EDGES + e];
        int pos = atomicAdd(&cursor4[(tid & 3) * N_NODES + d], 1);
        eid[pos] = e;
        return;
    }
    if (bid < 4725) {                        // zero agg|dxb (contiguous)
        size_t base = (size_t)(bid - 3125) * 1024 + (size_t)tid * 4;
#pragma unroll
        for (int k = 0; k < 4; ++k) {
            size_t i = base + k;
            if (i < ZERO_F4) zbase[i] = make_float4(0.f, 0.f, 0.f, 0.f);
        }
        return;
    }
    // ---- P/Q part ----
    const int lane = tid & 63;
    const int w = tid >> 6;
    const int lc = lane & 15;
    const int quad = lane >> 4;
    const int n0 = (bid - 4725) * 64;

#define STAGE_PQ(kc_, buf_) do {                                             \
        const int ko = (kc_) * 32 + (lane & 3) * 8;                          \
        const int row = w * 16 + (lane >> 2);                                \
        const int n = (n0 + row < N_NODES) ? n0 + row : N_NODES - 1;         \
        gl_lds16(h_bf + (size_t)n * 128 + ko, &sA[(buf_) * 2048 + w * 512]); \
    } while (0)

    STAGE_PQ(0, 0);
    const int ct0 = 2 * w, ct1 = 2 * w + 1;
    const int c0 = ct0 * 16 + lc, c1 = c0 + 16;
    const float bb0 = be1[c0], bb1 = be1[c1];

    floatx4 aP[4][2], aQ[4][2];
    // bias folded into P's accumulator init (MFMA C-in)
#pragma unroll
    for (int rt = 0; rt < 4; ++rt)
#pragma unroll
        for (int r = 0; r < 4; ++r) {
            aP[rt][0][r] = bb0; aP[rt][1][r] = bb1;
            aQ[rt][0][r] = 0.0f; aQ[rt][1][r] = 0.0f;
        }

    for (int kc = 0; kc < 4; ++kc) {
        __syncthreads();
        if (kc < 3) STAGE_PQ(kc + 1, (kc + 1) & 1);
        const int buf = kc & 1;
        bf16x8 bp0 = *(const bf16x8*)&pWe1[((size_t)(kc * 8 + ct0) * 64 + lane) * 8];
        bf16x8 bp1 = *(const bf16x8*)&pWe1[((size_t)(kc * 8 + ct1) * 64 + lane) * 8];
        bf16x8 bq0 = *(const bf16x8*)&pWe1[((size_t)((kc + 4) * 8 + ct0) * 64 + lane) * 8];
        bf16x8 bq1 = *(const bf16x8*)&pWe1[((size_t)((kc + 4) * 8 + ct1) * 64 + lane) * 8];
        __builtin_amdgcn_s_setprio(1);
#pragma unroll
        for (int rt = 0; rt < 4; ++rt) {
            bf16x8 a = *(const bf16x8*)&sA[buf * 2048 + (rt * 16 + lc) * 32 + quad * 8];
            aP[rt][0] = __builtin_amdgcn_mfma_f32_16x16x32_bf16(a, bp0, aP[rt][0], 0, 0, 0);
            aP[rt][1] = __builtin_amdgcn_mfma_f32_16x16x32_bf16(a, bp1, aP[rt][1], 0, 0, 0);
            aQ[rt][0] = __builtin_amdgcn_mfma_f32_16x16x32_bf16(a, bq0, aQ[rt][0], 0, 0, 0);
            aQ[rt][1] = __builtin_amdgcn_mfma_f32_16x16x32_bf16(a, bq1, aQ[rt][1], 0, 0, 0);
        }
        __builtin_amdgcn_s_setprio(0);
    }
    const int jid = w * 16 + lc;
#pragma unroll
    for (int rt = 0; rt < 4; ++rt)
#pragma unroll
        for (int r = 0; r < 4; ++r) {
            int n = n0 + rt * 16 + quad * 4 + r;
            if (n < N_NODES) {
                Pu[(size_t)n * 64 + jid] = cvt_pk_bf16(aP[rt][0][r], aP[rt][1][r]);
                Qu[(size_t)n * 64 + jid] = cvt_pk_bf16(aQ[rt][0][r], aQ[rt][1][r]);
            }
        }
#undef STAGE_PQ
}

// ==================== PRIMARY edge kernel (P/Q path, 128-tile, proven) ====================
__global__ __launch_bounds__(256, 4)
void egnn_edge_pq(const unsigned* __restrict__ Pu, const unsigned* __restrict__ Qu,
                  const float* __restrict__ x,
                  const int* __restrict__ ei, const float* __restrict__ ea,
                  const int* __restrict__ eid_sorted,
                  const short* __restrict__ pWe1, const short* __restrict__ pWe2,
                  const short* __restrict__ pWx1,
                  const float* __restrict__ be2,
                  const float* __restrict__ bx1, const float* __restrict__ Wx2,
                  const float* __restrict__ bx2,
                  float* __restrict__ agg, float* __restrict__ dxb) {
    __shared__ __align__(16) short sT[128 * 128];
    __shared__ __align__(16) int s_src[128];
    __shared__ __align__(16) int s_dst[128];
    __shared__ float s_dir[384], sGate[128];

    const int tid = threadIdx.x;
    const int lane = tid & 63;
    const int w = tid >> 6;
    const int lc = lane & 15;
    const int quad = lane >> 4;

    int bix = blockIdx.x;
    int bid = (bix < 6248) ? (bix & 7) * 781 + (bix >> 3) : bix;
    const int e0 = bid * 128;

    // preamble: indices, dist, dir
    int e_reg = 0; float dist_reg = 0.0f;
    if (tid < 128) {
        e_reg = eid_sorted[e0 + tid];
        int s = ei[e_reg], d = ei[N_EDGES + e_reg];
        s_src[tid] = s; s_dst[tid] = d;
        float ddx = x[d * 3 + 0] - x[s * 3 + 0];
        float ddy = x[d * 3 + 1] - x[s * 3 + 1];
        float ddz = x[d * 3 + 2] - x[s * 3 + 2];
        float dot = ddx * ddx + ddy * ddy + ddz * ddz;
        dist_reg = sqrtf(dot + 1e-9f);
        float inv = fast_rcp(sqrtf(dot) + 1e-9f);
        s_dir[tid * 3 + 0] = ddx * inv;
        s_dir[tid * 3 + 1] = ddy * inv;
        s_dir[tid * 3 + 2] = ddz * inv;
        sGate[tid] = 0.0f;
    }
    __syncthreads();   // (A) src/dst visible

    // stage the ea|dist K=32 chunk into sT[0..4096)
    if (tid < 128) {
        const float4* p = (const float4*)&ea[(size_t)e_reg * 16];
        float4 a = p[0], b = p[1], c = p[2], d = p[3];
        uint4* dst = (uint4*)&sT[tid * 32];
        dst[0] = make_uint4(cvt_pk_bf16(a.x, a.y), cvt_pk_bf16(a.z, a.w),
                            cvt_pk_bf16(b.x, b.y), cvt_pk_bf16(b.z, b.w));
        dst[1] = make_uint4(cvt_pk_bf16(c.x, c.y), cvt_pk_bf16(c.z, c.w),
                            cvt_pk_bf16(d.x, d.y), cvt_pk_bf16(d.z, d.w));
        dst[2] = make_uint4(cvt_pk_bf16(dist_reg, 0.0f), 0u, 0u, 0u);
        dst[3] = make_uint4(0u, 0u, 0u, 0u);
    }

    const int ct0 = 2 * w, ct1 = 2 * w + 1;
    const int c0 = ct0 * 16 + lc, c1 = c0 + 16;
    // paired-storage write coords for this lane
    const int jblk = w * 4 + (lc >> 2);
    const int joff = (lc & 3) * 2;

    // C-init: acc = P[src] + Q[dst]
    const unsigned jb = (unsigned)(w * 64 + lc * 4);   // byte offset within row
    floatx4 acc[8][2];
#pragma unroll
    for (int rt = 0; rt < 8; ++rt) {
        int4 ss = *(const int4*)&s_src[rt * 16 + quad * 4];
        int4 dd = *(const int4*)&s_dst[rt * 16 + quad * 4];
        unsigned p0 = *(const unsigned*)((const char*)Pu + ((unsigned)ss.x * 256u + jb));
        unsigned q0 = *(const unsigned*)((const char*)Qu + ((unsigned)dd.x * 256u + jb));
        unsigned p1 = *(const unsigned*)((const char*)Pu + ((unsigned)ss.y * 256u + jb));
        unsigned q1 = *(const unsigned*)((const char*)Qu + ((unsigned)dd.y * 256u + jb));
        unsigned p2 = *(const unsigned*)((const char*)Pu + ((unsigned)ss.z * 256u + jb));
        unsigned q2 = *(const unsigned*)((const char*)Qu + ((unsigned)dd.z * 256u + jb));
        unsigned p3 = *(const unsigned*)((const char*)Pu + ((unsigned)ss.w * 256u + jb));
        unsigned q3 = *(const unsigned*)((const char*)Qu + ((unsigned)dd.w * 256u + jb));
        acc[rt][0][0] = bflo(p0) + bflo(q0);
        acc[rt][1][0] = bfhi(p0) + bfhi(q0);
        acc[rt][0][1] = bflo(p1) + bflo(q1);
        acc[rt][1][1] = bfhi(p1) + bfhi(q1);
        acc[rt][0][2] = bflo(p2) + bflo(q2);
        acc[rt][1][2] = bfhi(p2) + bfhi(q2);
        acc[rt][0][3] = bflo(p3) + bflo(q3);
        acc[rt][1][3] = bfhi(p3) + bfhi(q3);
    }
    __syncthreads();   // (B) ea chunk staged

    // layer-1 remainder: single K=32 MFMA chunk (We1 rows 256..287 = chunk 8)
    {
        bf16x8 b0 = *(const bf16x8*)&pWe1[((size_t)(8 * 8 + ct0) * 64 + lane) * 8];
        bf16x8 b1 = *(const bf16x8*)&pWe1[((size_t)(8 * 8 + ct1) * 64 + lane) * 8];
        __builtin_amdgcn_s_setprio(1);
#pragma unroll
        for (int rt = 0; rt < 8; ++rt) {
            bf16x8 a = *(const bf16x8*)&sT[(rt * 16 + lc) * 32 + quad * 8];
            acc[rt][0] = __builtin_amdgcn_mfma_f32_16x16x32_bf16(a, b0, acc[rt][0], 0, 0, 0);
            acc[rt][1] = __builtin_amdgcn_mfma_f32_16x16x32_bf16(a, b1, acc[rt][1], 0, 0, 0);
        }
        __builtin_amdgcn_s_setprio(0);
    }
    __syncthreads();

    // epilogue 1: silu -> sT (bf16, permuted-paired, swizzled)
#pragma unroll
    for (int rt = 0; rt < 8; ++rt)
#pragma unroll
        for (int r = 0; r < 4; ++r) {
            int row = rt * 16 + quad * 4 + r;
            unsigned pk = cvt_pk_bf16(silu_f(acc[rt][0][r]), silu_f(acc[rt][1][r]));
            *(unsigned*)&sT[row * 128 + (jblk ^ ((row >> 1) & 7)) * 8 + joff] = pk;
        }
    __syncthreads();

    // ---- phi_e layer 2: m = t1 @ We2 + be2 (bias folded into acc init) ----
    {
        const float bb0 = be2[c0], bb1 = be2[c1];
#pragma unroll
        for (int rt = 0; rt < 8; ++rt)
#pragma unroll
            for (int r = 0; r < 4; ++r) {
                acc[rt][0][r] = bb0;
                acc[rt][1][r] = bb1;
            }
    }

    for (int kc = 0; kc < 4; ++kc) {
        bf16x8 b0 = *(const bf16x8*)&pWe2[((size_t)(kc * 8 + ct0) * 64 + lane) * 8];
        bf16x8 b1 = *(const bf16x8*)&pWe2[((size_t)(kc * 8 + ct1) * 64 + lane) * 8];
        __builtin_amdgcn_s_setprio(1);
#pragma unroll
        for (int rt = 0; rt < 8; ++rt) {
            int kb = (kc * 4 + quad) ^ ((lc >> 1) & 7);
            bf16x8 a = *(const bf16x8*)&sT[(rt * 16 + lc) * 128 + kb * 8];
            acc[rt][0] = __builtin_amdgcn_mfma_f32_16x16x32_bf16(a, b0, acc[rt][0], 0, 0, 0);
            acc[rt][1] = __builtin_amdgcn_mfma_f32_16x16x32_bf16(a, b1, acc[rt][1], 0, 0, 0);
        }
        __builtin_amdgcn_s_setprio(0);
    }
    __syncthreads();

    // write m -> sT (permuted-paired)
#pragma unroll
    for (int rt = 0; rt < 8; ++rt)
#pragma unroll
        for (int r = 0; r < 4; ++r) {
            int row = rt * 16 + quad * 4 + r;
            unsigned pk = cvt_pk_bf16(acc[rt][0][r], acc[rt][1][r]);
            *(unsigned*)&sT[row * 128 + (jblk ^ ((row >> 1) & 7)) * 8 + joff] = pk;
        }
    __syncthreads();

    // ---- phi_x (Wx1 K-rows permuted in pack; bx1 folded into acc init) ----
    {
        const float bb0 = bx1[c0], bb1 = bx1[c1];
#pragma unroll
        for (int rt = 0; rt < 8; ++rt)
#pragma unroll
            for (int r = 0; r < 4; ++r) {
                acc[rt][0][r] = bb0;
                acc[rt][1][r] = bb1;
            }
    }

    for (int kc = 0; kc < 4; ++kc) {
        bf16x8 b0 = *(const bf16x8*)&pWx1[((size_t)(kc * 8 + ct0) * 64 + lane) * 8];
        bf16x8 b1 = *(const bf16x8*)&pWx1[((size_t)(kc * 8 + ct1) * 64 + lane) * 8];
        __builtin_amdgcn_s_setprio(1);
#pragma unroll
        for (int rt = 0; rt < 8; ++rt) {
            int kb = (kc * 4 + quad) ^ ((lc >> 1) & 7);
            bf16x8 a = *(const bf16x8*)&sT[(rt * 16 + lc) * 128 + kb * 8];
            acc[rt][0] = __builtin_amdgcn_mfma_f32_16x16x32_bf16(a, b0, acc[rt][0], 0, 0, 0);
            acc[rt][1] = __builtin_amdgcn_mfma_f32_16x16x32_bf16(a, b1, acc[rt][1], 0, 0, 0);
        }
        __builtin_amdgcn_s_setprio(0);
    }

    // segmented agg scatter: paired column-walk (2 cols per thread, 32 rows)
    {
        const int sp = tid & 63;          // storage pair id
        const int rq = tid >> 6;          // row quarter
        const int cLo = ((sp >> 4) << 5) + (sp & 15);
        const int cHi = cLo + 16;
        const int pblk = sp >> 2;
        const int poff = (sp & 3) * 2;
        const int rb = rq * 32;
        float run0 = 0.0f, run1 = 0.0f;
        int cur = s_dst[rb];
#pragma unroll 8
        for (int r = rb; r < rb + 32; ++r) {
            int d = s_dst[r];
            if (d != cur) {
                atomicAdd(&agg[(size_t)cur * HDIM + cLo], run0);
                atomicAdd(&agg[(size_t)cur * HDIM + cHi], run1);
                run0 = 0.0f; run1 = 0.0f; cur = d;
            }
            unsigned v = *(const unsigned*)&sT[r * 128 + (pblk ^ ((r >> 1) & 7)) * 8 + poff];
            run0 += bflo(v); run1 += bfhi(v);
        }
        atomicAdd(&agg[(size_t)cur * HDIM + cLo], run0);
        atomicAdd(&agg[(size_t)cur * HDIM + cHi], run1);
    }

    // gate epilogue (bx1 already in acc)
    {
        float wx0 = Wx2[c0], wx1 = Wx2[c1];
        float gp[8][4];
#pragma unroll
        for (int rt = 0; rt < 8; ++rt)
#pragma unroll
            for (int r = 0; r < 4; ++r)
                gp[rt][r] = silu_f(acc[rt][0][r]) * wx0 +
                            silu_f(acc[rt][1][r]) * wx1;
#pragma unroll
        for (int m = 1; m < 16; m <<= 1)
#pragma unroll
            for (int rt = 0; rt < 8; ++rt)
#pragma unroll
                for (int r = 0; r < 4; ++r)
                    gp[rt][r] += __shfl_xor(gp[rt][r], m, 64);
        if (lc == 0) {
#pragma unroll
            for (int rt = 0; rt < 8; ++rt)
#pragma unroll
                for (int r = 0; r < 4; ++r)
                    atomicAdd(&sGate[rt * 16 + quad * 4 + r], gp[rt][r]);
        }
    }
    __syncthreads();

    // segmented dx scatter
    if (tid < 48) {
        const int comp = tid % 3;
        const int ch = tid / 3;
        const float b2 = bx2[0];
        int r = ch * 8;
        float run = 0.0f;
        int cur = s_dst[r];
        for (int k = 0; k < 8; ++k, ++r) {
            int d = s_dst[r];
            if (d != cur) {
                atomicAdd(&dxb[(size_t)cur * 3 + comp], run);
                run = 0.0f; cur = d;
            }
            run += s_dir[r * 3 + comp] * (sGate[r] + b2);
        }
        atomicAdd(&dxb[(size_t)cur * 3 + comp], run);
    }
}

// ==================== FALLBACK edge kernel (128-tile, unchanged) ====================
__global__ __launch_bounds__(256, 4)
void egnn_edge_v4(const short* __restrict__ h_bf, const float* __restrict__ x,
                  const int* __restrict__ ei, const float* __restrict__ ea,
                  const int* __restrict__ eid_sorted,
                  const short* __restrict__ pWe1, const short* __restrict__ pWe2,
                  const short* __restrict__ pWx1,
                  const float* __restrict__ be1, const float* __restrict__ be2,
                  const float* __restrict__ bx1, const float* __restrict__ Wx2,
                  const float* __restrict__ bx2,
                  float* __restrict__ agg, float* __restrict__ dxb) {
    __shared__ __align__(16) short sT[128 * 128];
    __shared__ int s_dst[128], s_eid[128];
    __shared__ float s_dist[128], s_dir[384], sGate[128];

    const int tid = threadIdx.x;
    const int lane = tid & 63;
    const int w = tid >> 6;
    const int lc = lane & 15;
    const int quad = lane >> 4;

    int bix = blockIdx.x;
    int bid = (bix < 6248) ? (bix & 7) * 781 + (bix >> 3) : bix;
    const int e0 = bid * 128;

    const int part = lane & 3;
    const int r0 = w * 32 + (lane >> 2);
    const int r1 = r0 + 16;
    const int eS0 = eid_sorted[e0 + r0], eS1 = eid_sorted[e0 + r1];
    const int es0 = ei[eS0], ed0 = ei[N_EDGES + eS0];
    const int es1 = ei[eS1], ed1 = ei[N_EDGES + eS1];

#define STAGE_H(kc_, buf_) do {                                              \
        const int ss = ((kc_) < 4);                                          \
        const int ko = ((kc_) & 3) * 32 + part * 8;                          \
        gl_lds16(h_bf + (size_t)(ss ? es0 : ed0) * 128 + ko,                 \
                 &sT[(buf_) * 4096 + w * 1024]);                             \
        gl_lds16(h_bf + (size_t)(ss ? es1 : ed1) * 128 + ko,                 \
                 &sT[(buf_) * 4096 + w * 1024 + 512]);                       \
    } while (0)

    STAGE_H(0, 0);

    if (tid < 128) {
        int e = eid_sorted[e0 + tid];
        s_eid[tid] = e;
        int s = ei[e], d = ei[N_EDGES + e];
        s_dst[tid] = d;
        float ddx = x[d * 3 + 0] - x[s * 3 + 0];
        float ddy = x[d * 3 + 1] - x[s * 3 + 1];
        float ddz = x[d * 3 + 2] - x[s * 3 + 2];
        float dot = ddx * ddx + ddy * ddy + ddz * ddz;
        s_dist[tid] = sqrtf(dot + 1e-9f);
        float inv = fast_rcp(sqrtf(dot) + 1e-9f);
        s_dir[tid * 3 + 0] = ddx * inv;
        s_dir[tid * 3 + 1] = ddy * inv;
        s_dir[tid * 3 + 2] = ddz * inv;
        sGate[tid] = 0.0f;
    }

    const int ct0 = 2 * w, ct1 = 2 * w + 1;
    const int c0 = ct0 * 16 + lc, c1 = c0 + 16;
    const int jblk = w * 4 + (lc >> 2);
    const int joff = (lc & 3) * 2;

    floatx4 acc[8][2];
#pragma unroll
    for (int rt = 0; rt < 8; ++rt)
#pragma unroll
        for (int ct = 0; ct < 2; ++ct)
#pragma unroll
            for (int r = 0; r < 4; ++r) acc[rt][ct][r] = 0.0f;

    for (int kc = 0; kc < 9; ++kc) {
        __syncthreads();
        if (kc < 7) {
            STAGE_H(kc + 1, (kc + 1) & 1);
        } else if (kc == 7) {
            if (tid < 128) {
                const float4* p = (const float4*)&ea[(size_t)s_eid[tid] * 16];
                float4 a = p[0], b = p[1], c = p[2], d = p[3];
                uint4* dst = (uint4*)&sT[0 * 4096 + tid * 32];
                dst[0] = make_uint4(cvt_pk_bf16(a.x, a.y), cvt_pk_bf16(a.z, a.w),
                                    cvt_pk_bf16(b.x, b.y), cvt_pk_bf16(b.z, b.w));
                dst[1] = make_uint4(cvt_pk_bf16(c.x, c.y), cvt_pk_bf16(c.z, c.w),
                                    cvt_pk_bf16(d.x, d.y), cvt_pk_bf16(d.z, d.w));
                dst[2] = make_uint4(cvt_pk_bf16(s_dist[tid], 0.0f), 0u, 0u, 0u);
                dst[3] = make_uint4(0u, 0u, 0u, 0u);
            }
        }
        const int buf = kc & 1;
        bf16x8 b0 = *(const bf16x8*)&pWe1[((size_t)(kc * 8 + ct0) * 64 + lane) * 8];
        bf16x8 b1 = *(const bf16x8*)&pWe1[((size_t)(kc * 8 + ct1) * 64 + lane) * 8];
#pragma unroll
        for (int rt = 0; rt < 8; ++rt) {
            bf16x8 a = *(const bf16x8*)&sT[buf * 4096 + (rt * 16 + lc) * 32 + quad * 8];
            acc[rt][0] = __builtin_amdgcn_mfma_f32_16x16x32_bf16(a, b0, acc[rt][0], 0, 0, 0);
            acc[rt][1] = __builtin_amdgcn_mfma_f32_16x16x32_bf16(a, b1, acc[rt][1], 0, 0, 0);
        }
    }
    __syncthreads();

    {
        float bb0 = be1[c0], bb1 = be1[c1];
#pragma unroll
        for (int rt = 0; rt < 8; ++rt)
#pragma unroll
            for (int r = 0; r < 4; ++r) {
                int row = rt * 16 + quad * 4 + r;
                unsigned pk = cvt_pk_bf16(silu_f(acc[rt][0][r] + bb0),
                                          silu_f(acc[rt][1][r] + bb1));
                *(unsigned*)&sT[row * 128 + (jblk ^ ((row >> 1) & 7)) * 8 + joff] = pk;
            }
    }
    __syncthreads();

#pragma unroll
    for (int rt = 0; rt < 8; ++rt)
#pragma unroll
        for (int ct = 0; ct < 2; ++ct)
#pragma unroll
            for (int r = 0; r < 4; ++r) acc[rt][ct][r] = 0.0f;

    for (int kc = 0; kc < 4; ++kc) {
        bf16x8 b0 = *(const bf16x8*)&pWe2[((size_t)(kc * 8 + ct0) * 64 + lane) * 8];
        bf16x8 b1 = *(const bf16x8*)&pWe2[((size_t)(kc * 8 + ct1) * 64 + lane) * 8];
#pragma unroll
        for (int rt = 0; rt < 8; ++rt) {
            int kb = (kc * 4 + quad) ^ ((lc >> 1) & 7);
            bf16x8 a = *(const bf16x8*)&sT[(rt * 16 + lc) * 128 + kb * 8];
            acc[rt][0] = __builtin_amdgcn_mfma_f32_16x16x32_bf16(a, b0, acc[rt][0], 0, 0, 0);
            acc[rt][1] = __builtin_amdgcn_mfma_f32_16x16x32_bf16(a, b1, acc[rt][1], 0, 0, 0);
        }
    }
    __syncthreads();

    {
        float bb0 = be2[c0], bb1 = be2[c1];
#pragma unroll
        for (int rt = 0; rt < 8; ++rt)
#pragma unroll
            for (int r = 0; r < 4; ++r) {
                int row = rt * 16 + quad * 4 + r;
                unsigned pk = cvt_pk_bf16(acc[rt][0][r] + bb0, acc[rt][1][r] + bb1);
                *(unsigned*)&sT[row * 128 + (jblk ^ ((row >> 1) & 7)) * 8 + joff] = pk;
            }
    }
    __syncthreads();

#pragma unroll
    for (int rt = 0; rt < 8; ++rt)
#pragma unroll
        for (int ct = 0; ct < 2; ++ct)
#pragma unroll
            for (int r = 0; r < 4; ++r) acc[rt][ct][r] = 0.0f;

    for (int kc = 0; kc < 4; ++kc) {
        bf16x8 b0 = *(const bf16x8*)&pWx1[((size_t)(kc * 8 + ct0) * 64 + lane) * 8];
        bf16x8 b1 = *(const bf16x8*)&pWx1[((size_t)(kc * 8 + ct1) * 64 + lane) * 8];
#pragma unroll
        for (int rt = 0; rt < 8; ++rt) {
            int kb = (kc * 4 + quad) ^ ((lc >> 1) & 7);
            bf16x8 a = *(const bf16x8*)&sT[(rt * 16 + lc) * 128 + kb * 8];
            acc[rt][0] = __builtin_amdgcn_mfma_f32_16x16x32_bf16(a, b0, acc[rt][0], 0, 0, 0);
            acc[rt][1] = __builtin_amdgcn_mfma_f32_16x16x32_bf16(a, b1, acc[rt][1], 0, 0, 0);
        }
    }

    {
        const int sp = tid & 63;
        const int rq = tid >> 6;
        const int cLo = ((sp >> 4) << 5) + (sp & 15);
        const int cHi = cLo + 16;
        const int pblk = sp >> 2;
        const int poff = (sp & 3) * 2;
        const int rb = rq * 32;
        float run0 = 0.0f, run1 = 0.0f;
        int cur = s_dst[rb];
#pragma unroll 8
        for (int r = rb; r < rb + 32; ++r) {
            int d = s_dst[r];
            if (d != cur) {
                atomicAdd(&agg[(size_t)cur * HDIM + cLo], run0);
                atomicAdd(&agg[(size_t)cur * HDIM + cHi], run1);
                run0 = 0.0f; run1 = 0.0f; cur = d;
            }
            unsigned v = *(const unsigned*)&sT[r * 128 + (pblk ^ ((r >> 1) & 7)) * 8 + poff];
            run0 += bflo(v); run1 += bfhi(v);
        }
        atomicAdd(&agg[(size_t)cur * HDIM + cLo], run0);
        atomicAdd(&agg[(size_t)cur * HDIM + cHi], run1);
    }

    {
        float wx0 = Wx2[c0], wx1 = Wx2[c1];
        float bb0 = bx1[c0], bb1 = bx1[c1];
        float gp[8][4];
#pragma unroll
        for (int rt = 0; rt < 8; ++rt)
#pragma unroll
            for (int r = 0; r < 4; ++r)
                gp[rt][r] = silu_f(acc[rt][0][r] + bb0) * wx0 +
                            silu_f(acc[rt][1][r] + bb1) * wx1;
#pragma unroll
        for (int m = 1; m < 16; m <<= 1)
#pragma unroll
            for (int rt = 0; rt < 8; ++rt)
#pragma unroll
                for (int r = 0; r < 4; ++r)
                    gp[rt][r] += __shfl_xor(gp[rt][r], m, 64);
        if (lc == 0) {
#pragma unroll
            for (int rt = 0; rt < 8; ++rt)
#pragma unroll
                for (int r = 0; r < 4; ++r)
                    atomicAdd(&sGate[rt * 16 + quad * 4 + r], gp[rt][r]);
        }
    }
    __syncthreads();

    if (tid < 48) {
        const int comp = tid % 3;
        const int ch = tid / 3;
        const float b2 = bx2[0];
        int r = ch * 8;
        float run = 0.0f;
        int cur = s_dst[r];
        for (int k = 0; k < 8; ++k, ++r) {
            int d = s_dst[r];
            if (d != cur) {
                atomicAdd(&dxb[(size_t)cur * 3 + comp], run);
                run = 0.0f; cur = d;
            }
            run += s_dir[r * 3 + comp] * (sGate[r] + b2);
        }
        atomicAdd(&dxb[(size_t)cur * 3 + comp], run);
    }
#undef STAGE_H
}

__global__ __launch_bounds__(256, 4)
void egnn_node_mfma(const short* __restrict__ h_bf, const float* __restrict__ h,
                    const float* __restrict__ x,
                    const float* __restrict__ agg, const float* __restrict__ dxb,
                    const short* __restrict__ pWh1, const short* __restrict__ pWh2,
                    const float* __restrict__ bh1, const float* __restrict__ bh2,
                    const float* __restrict__ ln_g, const float* __restrict__ ln_b,
                    float* __restrict__ hout, float* __restrict__ xout) {
    __shared__ __align__(16) short sT[64 * 128];
    __shared__ float sS1[64], sS2[64];

    const int tid = threadIdx.x;
    const int lane = tid & 63;
    const int w = tid >> 6;
    const int lc = lane & 15;
    const int quad = lane >> 4;
    const int n0 = blockIdx.x * 64;

#define STAGE_N(kc_, buf_) do {                                              \
        if ((kc_) < 4) {                                                     \
            const int ko = (kc_) * 32 + (lane & 3) * 8;                      \
            const int row = w * 16 + (lane >> 2);                            \
            const int n = (n0 + row < N_NODES) ? n0 + row : N_NODES - 1;     \
            gl_lds16(h_bf + (size_t)n * 128 + ko,                            \
                     &sT[(buf_) * 2048 + w * 512]);                          \
        } else {                                                             \
            const int srow = tid >> 2, prt = tid & 3;                        \
            const int n = (n0 + srow < N_NODES) ? n0 + srow : N_NODES - 1;   \
            const float4* p = (const float4*)&agg[(size_t)n * HDIM +         \
                                                  ((kc_) & 3) * 32 + prt * 8]; \
            float4 a = p[0], b = p[1];                                       \
            *(uint4*)&sT[(buf_) * 2048 + srow * 32 + prt * 8] =              \
                make_uint4(cvt_pk_bf16(a.x, a.y), cvt_pk_bf16(a.z, a.w),     \
                           cvt_pk_bf16(b.x, b.y), cvt_pk_bf16(b.z, b.w));    \
        }                                                                    \
    } while (0)

    STAGE_N(0, 0);
    if (tid < 64) { sS1[tid] = 0.0f; sS2[tid] = 0.0f; }

    const int ct0 = 2 * w, ct1 = 2 * w + 1;
    const int c0 = ct0 * 16 + lc, c1 = c0 + 16;
    const int jblk = w * 4 + (lc >> 2);
    const int joff = (lc & 3) * 2;

    floatx4 acc[4][2];
    // bh1 folded into acc init
    {
        const float bb0 = bh1[c0], bb1 = bh1[c1];
#pragma unroll
        for (int rt = 0; rt < 4; ++rt)
#pragma unroll
            for (int r = 0; r < 4; ++r) {
                acc[rt][0][r] = bb0;
                acc[rt][1][r] = bb1;
            }
    }

    for (int kc = 0; kc < 8; ++kc) {
        __syncthreads();
        if (kc < 7) STAGE_N(kc + 1, (kc + 1) & 1);
        const int buf = kc & 1;
        bf16x8 b0 = *(const bf16x8*)&pWh1[((size_t)(kc * 8 + ct0) * 64 + lane) * 8];
        bf16x8 b1 = *(const bf16x8*)&pWh1[((size_t)(kc * 8 + ct1) * 64 + lane) * 8];
        __builtin_amdgcn_s_setprio(1);
#pragma unroll
        for (int rt = 0; rt < 4; ++rt) {
            bf16x8 a = *(const bf16x8*)&sT[buf * 2048 + (rt * 16 + lc) * 32 + quad * 8];
            acc[rt][0] = __builtin_amdgcn_mfma_f32_16x16x32_bf16(a, b0, acc[rt][0], 0, 0, 0);
            acc[rt][1] = __builtin_amdgcn_mfma_f32_16x16x32_bf16(a, b1, acc[rt][1], 0, 0, 0);
        }
        __builtin_amdgcn_s_setprio(0);
    }
    __syncthreads();

#pragma unroll
    for (int rt = 0; rt < 4; ++rt)
#pragma unroll
        for (int r = 0; r < 4; ++r) {
            int row = rt * 16 + quad * 4 + r;
            unsigned pk = cvt_pk_bf16(silu_f(acc[rt][0][r]), silu_f(acc[rt][1][r]));
            *(unsigned*)&sT[row * 128 + (jblk ^ ((row >> 1) & 7)) * 8 + joff] = pk;
        }
    __syncthreads();

    // bh2 folded into acc init
    {
        const float bb0 = bh2[c0], bb1 = bh2[c1];
#pragma unroll
        for (int rt = 0; rt < 4; ++rt)
#pragma unroll
            for (int r = 0; r < 4; ++r) {
                acc[rt][0][r] = bb0;
                acc[rt][1][r] = bb1;
            }
    }

    for (int kc = 0; kc < 4; ++kc) {
        bf16x8 b0 = *(const bf16x8*)&pWh2[((size_t)(kc * 8 + ct0) * 64 + lane) * 8];
        bf16x8 b1 = *(const bf16x8*)&pWh2[((size_t)(kc * 8 + ct1) * 64 + lane) * 8];
        __builtin_amdgcn_s_setprio(1);
#pragma unroll
        for (int rt = 0; rt < 4; ++rt) {
            int kb = (kc * 4 + quad) ^ ((lc >> 1) & 7);
            bf16x8 a = *(const bf16x8*)&sT[(rt * 16 + lc) * 128 + kb * 8];
            acc[rt][0] = __builtin_amdgcn_mfma_f32_16x16x32_bf16(a, b0, acc[rt][0], 0, 0, 0);
            acc[rt][1] = __builtin_amdgcn_mfma_f32_16x16x32_bf16(a, b1, acc[rt][1], 0, 0, 0);
        }
        __builtin_amdgcn_s_setprio(0);
    }

    {
#pragma unroll
        for (int rt = 0; rt < 4; ++rt)
#pragma unroll
            for (int r = 0; r < 4; ++r) {
                int row = rt * 16 + quad * 4 + r;
                int n = n0 + row;
                int nc = (n < N_NODES) ? n : (N_NODES - 1);
                float v0 = acc[rt][0][r] + h[(size_t)nc * HDIM + c0];
                float v1 = acc[rt][1][r] + h[(size_t)nc * HDIM + c1];
                acc[rt][0][r] = v0;
                acc[rt][1][r] = v1;
                float s1 = v0 + v1;
                float s2 = v0 * v0 + v1 * v1;
#pragma unroll
                for (int m = 1; m < 16; m <<= 1) {
                    s1 += __shfl_xor(s1, m, 64);
                    s2 += __shfl_xor(s2, m, 64);
                }
                if (lc == 0) {
                    atomicAdd(&sS1[row], s1);
                    atomicAdd(&sS2[row], s2);
                }
            }
    }
    __syncthreads();
    {
        float g0 = ln_g[c0], g1 = ln_g[c1];
        float lb0 = ln_b[c0], lb1 = ln_b[c1];
#pragma unroll
        for (int rt = 0; rt < 4; ++rt)
#pragma unroll
            for (int r = 0; r < 4; ++r) {
                int row = rt * 16 + quad * 4 + r;
                int n = n0 + row;
                if (n < N_NODES) {
                    float mu = sS1[row] * (1.0f / 128.0f);
                    float var = sS2[row] * (1.0f / 128.0f) - mu * mu;
                    float rs = rsqrtf(var + 1e-5f);
                    hout[(size_t)n * HDIM + c0] = (acc[rt][0][r] - mu) * rs * g0 + lb0;
                    hout[(size_t)n * HDIM + c1] = (acc[rt][1][r] - mu) * rs * g1 + lb1;
                }
            }
    }

    if (tid < 192) {
        int n = n0 + tid / 3;
        int d = tid - (tid / 3) * 3;
        if (n < N_NODES) xout[(size_t)n * 3 + d] = x[(size_t)n * 3 + d] + dxb[(size_t)n * 3 + d];
    }
#undef STAGE_N
}

extern "C" void kernel_launch(void* const* d_in, const int* in_sizes, int n_in,
                              void* d_out, int out_size, void* d_ws, size_t ws_size,
                              hipStream_t stream) {
    (void)in_sizes; (void)n_in; (void)out_size;

    const float* h   = (const float*)d_in[0];
    const float* x   = (const float*)d_in[1];
    const int*   ei  = (const int*)d_in[2];
    const float* ea  = (const float*)d_in[3];
    const float* We1 = (const float*)d_in[4];
    const float* be1 = (const float*)d_in[5];
    const float* We2 = (const float*)d_in[6];
    const float* be2 = (const float*)d_in[7];
    const float* Wh1 = (const float*)d_in[8];
    const float* bh1 = (const float*)d_in[9];
    const float* Wh2 = (const float*)d_in[10];
    const float* bh2 = (const float*)d_in[11];
    const float* Wx1 = (const float*)d_in[12];
    const float* bx1 = (const float*)d_in[13];
    const float* Wx2 = (const float*)d_in[14];
    const float* bx2 = (const float*)d_in[15];
    const float* lng = (const float*)d_in[16];
    const float* lnb = (const float*)d_in[17];

    float* hout = (float*)d_out;
    float* xout = hout + (size_t)N_NODES * HDIM;

    const size_t CH = 8 * 64 * 8;
    const size_t oWe1 = 0, oWh1 = 17 * CH, oWh2 = 25 * CH;
    const size_t oWe2 = 9 * CH, oWx1 = 13 * CH;
    const size_t pwElems = 29 * CH;

    const size_t aggElems = (size_t)N_NODES * HDIM;
    const size_t dxbElems = (size_t)N_NODES * 3;
    const size_t aggB = aggElems * 4, dxbB = dxbElems * 4;
    const size_t pwB = pwElems * 2;
    const size_t hbB = (size_t)N_NODES * HDIM * 2;
    const size_t cntB = (size_t)N_NODES * 4;
    const size_t eidB = (size_t)N_EDGES * 4;

    char* ws = (char*)d_ws;
    // bigws needs 4-shadow cnt + 4-shadow cursor (8 * cntB)
    const bool bigws = ws_size >= aggB + dxbB + pwB + hbB + 8 * cntB + eidB;

    float* agg; float* dxb; short* pw; short* h_bf; int* cnt; int* cursor; int* eid;
    if (bigws) {
        agg    = (float*)ws;
        dxb    = (float*)(ws + aggB);
        pw     = (short*)(ws + aggB + dxbB);
        h_bf   = (short*)(ws + aggB + dxbB + pwB);
        cnt    = (int*)(ws + aggB + dxbB + pwB + hbB);                 // cnt4[4][N]
        cursor = (int*)(ws + aggB + dxbB + pwB + hbB + 4 * cntB);      // cursor4[4][N]
        eid    = (int*)(ws + aggB + dxbB + pwB + hbB + 8 * cntB);
    } else {
        pw     = (short*)ws;
        h_bf   = (short*)(ws + pwB);
        cnt    = (int*)(ws + pwB + hbB);
        cursor = (int*)(ws + pwB + hbB + cntB);
        eid    = (int*)(ws + pwB + hbB + 2 * cntB);
        agg    = (float*)d_out;    // aliasing safe: node blocks read their agg/
        dxb    = agg + aggElems;   // dxb rows before writing hout/xout rows
    }

    if (bigws) {
        // P/Q live in d_out (free scratch until node kernel writes hout/xout)
        unsigned* Pu = (unsigned*)d_out;
        unsigned* Qu = Pu + (size_t)N_NODES * 64;

        hipMemsetAsync(cnt, 0, 4 * cntB, stream);
        // hist (4-shadow) | pack h | pack weights
        fused_prep1<<<6308, 256, 0, stream>>>(h, h_bf, We1, We2, Wx1, Wh1, Wh2,
                                              pw, ei, cnt);
        scan4_kernel<<<1, 1024, 0, stream>>>(cnt, cursor, N_NODES / 4);
        // scatter (4-shadow) | zero agg+dxb (contiguous) | P/Q precompute
        fused_prep2<<<5507, 256, 0, stream>>>(ei, cursor, eid, h_bf, pw + oWe1,
                                              be1, Pu, Qu, (float4*)agg);
        egnn_edge_pq<<<N_EDGES / 128, 256, 0, stream>>>(
            Pu, Qu, x, ei, ea, eid, pw + oWe1, pw + oWe2, pw + oWx1,
            be2, bx1, Wx2, bx2, agg, dxb);
    } else {
        hipMemsetAsync(agg, 0, aggB, stream);
        hipMemsetAsync(dxb, 0, dxbB, stream);
        hipMemsetAsync(cnt, 0, cntB, stream);
        pack_bf16_kernel<<<(N_NODES * HDIM / 8 + 255) / 256, 256, 0, stream>>>(
            h, h_bf, N_NODES * HDIM / 8);
        pack_all_w<<<(29 * 512 + 255) / 256, 256, 0, stream>>>(We1, We2, Wx1, Wh1, Wh2, pw);
        hist_kernel<<<(N_EDGES + 255) / 256, 256, 0, stream>>>(ei, cnt);
        scan_kernel<<<1, 1024, 0, stream>>>(cnt, cursor, N_NODES / 4);
        scatter_kernel<<<(N_EDGES + 255) / 256, 256, 0, stream>>>(ei, cursor, eid);
        egnn_edge_v4<<<N_EDGES / 128, 256, 0, stream>>>(
            h_bf, x, ei, ea, eid, pw + oWe1, pw + oWe2, pw + oWx1,
            be1, be2, bx1, Wx2, bx2, agg, dxb);
    }

    egnn_node_mfma<<<(N_NODES + 63) / 64, 256, 0, stream>>>(
        h_bf, h, x, agg, dxb, pw + oWh1, pw + oWh2,
        bh1, bh2, lng, lnb, hout, xout);
}